// Round 10
// baseline (1014.957 us; speedup 1.0000x reference)
//
#include <hip/hip_runtime.h>

// Problem constants (AttentionalCopula)
constexpr int kB = 16, kD = 256, kNH = 512, kNV = 256, kW = 768;
constexpr int kL = 4, kH = 8, kA = 64, kHA = 512, kM = 512, kR = 128;
constexpr int kKP = 288;  // K=257 zero-padded to multiple of 32
constexpr int kRows = kB * kNV;  // 4096

typedef __bf16 bf16x8 __attribute__((ext_vector_type(8)));
typedef __bf16 bf16x4 __attribute__((ext_vector_type(4)));
typedef float f32x4 __attribute__((ext_vector_type(4)));

__device__ inline void load_lds16(const __bf16* g, __bf16* l) {
  __builtin_amdgcn_global_load_lds(
      (const __attribute__((address_space(1))) void*)g,
      (__attribute__((address_space(3))) void*)l, 16, 0, 0);
}

// ---------------- merged prep kernel (1 launch, block-range sections) --------
constexpr int kP1 = kB * kW * kKP;  // 3,538,944 -> 13824 blocks
constexpr int kPrepBlocks = 17683;

__global__ void prep_kernel(const float* __restrict__ hist,
                            const float* __restrict__ hist_u,
                            const float* __restrict__ pred,
                            const float* __restrict__ pred_u,
                            const float* __restrict__ kw,
                            const float* __restrict__ vw,
                            const float* __restrict__ w1,
                            const float* __restrict__ w2,
                            const float* __restrict__ w3,
                            const float* __restrict__ ds_w,
                            const float* __restrict__ de_w,
                            const float* __restrict__ key_b,
                            const float* __restrict__ val_b,
                            __bf16* __restrict__ ki,
                            __bf16* __restrict__ kvwt,
                            __bf16* __restrict__ ffwt,
                            __bf16* __restrict__ ds_wt,
                            __bf16* __restrict__ de_wt,
                            float* __restrict__ kvb,
                            float* __restrict__ outz,
                            int* __restrict__ flagsz) {
  __shared__ float ld[2080];  // 32x65 (B) / 32x33 (C,D,E)
  const int bid = blockIdx.x;
  const int t = threadIdx.x;
  if (bid < 13824) {
    // ---- A: ki fill ----
    int i = bid * 256 + t;
    int d = i % kKP;
    int bw = i / kKP;
    int w = bw % kW;
    int b = bw / kW;
    float v = 0.f;
    if (d < 257) {
      if (w < kNH)
        v = (d < kD) ? hist[((size_t)b * kNH + w) * kD + d] : hist_u[b * kNH + w];
      else {
        int p = w - kNH;
        v = (d < kD) ? pred[((size_t)b * kNV + p) * kD + d] : pred_u[b * kNV + p];
      }
    }
    ki[i] = (__bf16)v;
  } else if (bid < 14400) {
    // ---- B: kv weight transpose ----
    int bb = bid - 13824;
    bool isv = bb >= 288;
    int rem = isv ? bb - 288 : bb;
    int pair = rem / 9;
    int dt = rem - pair * 9;
    int d0 = dt * 32;
    const float* src = (isv ? vw : kw) + (size_t)pair * 257 * 64;
    int a = t & 63, dg = t >> 6;
#pragma unroll
    for (int ii = 0; ii < 8; ++ii) {
      int d = d0 + dg * 8 + ii;
      ld[(dg * 8 + ii) * 65 + a] = (d < 257) ? src[(size_t)d * 64 + a] : 0.f;
    }
    __syncthreads();
    int r = t >> 2, seg = t & 3;
    bf16x8 v;
#pragma unroll
    for (int j = 0; j < 8; ++j) v[j] = (__bf16)ld[(seg * 8 + j) * 65 + r];
    *(bf16x8*)&kvwt[((size_t)(isv ? 2048 : 0) + pair * 64 + r) * 288 + d0 +
                    seg * 8] = v;
  } else if (bid < 17472) {
    // ---- C: ff weight transpose ----
    int cc = bid - 14400;
    int mat = cc >> 8;
    int tile = cc & 255;
    int n0 = (tile & 15) * 32, k0 = (tile >> 4) * 32;
    int l = mat / 3, which = mat - l * 3;
    const float* src = (which == 0 ? w1 : which == 1 ? w2 : w3) +
                       (size_t)l * 262144;
    int col = t & 31, kr = t >> 5;
#pragma unroll
    for (int p = 0; p < 4; ++p)
      ld[(kr + p * 8) * 33 + col] = src[(size_t)(k0 + kr + p * 8) * 512 + n0 + col];
    __syncthreads();
    int nr = t >> 3, seg = t & 7;
    bf16x4 v;
#pragma unroll
    for (int j = 0; j < 4; ++j) v[j] = (__bf16)ld[(seg * 4 + j) * 33 + nr];
    *(bf16x4*)&ffwt[(size_t)mat * 262144 + (n0 + nr) * 512 + k0 + seg * 4] = v;
  } else if (bid < 17600) {
    // ---- D: ds_w transpose ----
    int cc = bid - 17472;
    int n0 = (cc & 15) * 32, k0 = (cc >> 4) * 32;
    int col = t & 31, kr = t >> 5;
#pragma unroll
    for (int p = 0; p < 4; ++p)
      ld[(kr + p * 8) * 33 + col] = ds_w[(size_t)(k0 + kr + p * 8) * 512 + n0 + col];
    __syncthreads();
    int nr = t >> 3, seg = t & 7;
    bf16x4 v;
#pragma unroll
    for (int j = 0; j < 4; ++j) v[j] = (__bf16)ld[(seg * 4 + j) * 33 + nr];
    *(bf16x4*)&ds_wt[(n0 + nr) * 256 + k0 + seg * 4] = v;
  } else if (bid < 17664) {
    // ---- E: de_w transpose ----
    int cc = bid - 17600;
    int n0 = (cc & 3) * 32, k0 = (cc >> 2) * 32;
    int col = t & 31, kr = t >> 5;
#pragma unroll
    for (int p = 0; p < 4; ++p)
      ld[(kr + p * 8) * 33 + col] = de_w[(size_t)(k0 + kr + p * 8) * 128 + n0 + col];
    __syncthreads();
    int nr = t >> 3, seg = t & 7;
    bf16x4 v;
#pragma unroll
    for (int j = 0; j < 4; ++j) v[j] = (__bf16)ld[(seg * 4 + j) * 33 + nr];
    *(bf16x4*)&de_wt[(n0 + nr) * 512 + k0 + seg * 4] = v;
  } else {
    // ---- F: kvb + out zero + flags zero ----
    int j = (bid - 17664) * 256 + t;
    if (j < 4096) {
      bool isv = j >= 2048;
      int cc = isv ? j - 2048 : j;
      int l = cc >> 9, rest = cc & 511;
      kvb[j] = isv ? val_b[l * 512 + rest] : key_b[l * 512 + rest];
    } else if (j < 4112) {
      outz[j - 4096] = 0.f;
    } else if (j < 4624) {
      flagsz[j - 4112] = 0;
    }
  }
}

// ---- generic bf16 MFMA GEMM core (DEPTH-buffer counted-vmcnt pipeline) ------
template <int BN, int OMODE, bool RELU, bool KIMAP, bool BIASROW, int DEPTH>
__device__ __forceinline__ void gemm_core(
    int bxv, int byv, const __bf16* __restrict__ A,
    const __bf16* __restrict__ Bt, const float* __restrict__ bias,
    void* __restrict__ Cout, __bf16* __restrict__ Cout2, int K, int lda,
    int ldc, __bf16* Sm) {
  constexpr int JN = BN / 32;
  constexpr int BROWS = BN / 4;
  constexpr int SSTEP = (128 + BN) * 32;
  constexpr int LPS = (BN == 128) ? 4 : 3;
  constexpr int AH = DEPTH - 1;
  const int t = threadIdx.x;
  const int wid = t >> 6;
  const int lane = t & 63;
  const int bm = byv * 128;
  const int bn = bxv * BN;
  const int wm = (wid >> 1) * 64;
  const int wn = (wid & 1) * (BN / 2);
  const int sr = lane >> 2, sc = lane & 3;
  const int skey = (sr >> 1) & 3;
  const int abase = KIMAP ? ((bm >> 8) * 768 + 512 + (bm & 255)) : bm;
  const __bf16* Ag = A + (size_t)(abase + wid * 32 + sr) * lda + (sc ^ skey) * 8;
  const __bf16* Bg = Bt + (size_t)(bn + wid * BROWS + sr) * K + (sc ^ skey) * 8;

  auto stage = [&](int k0, __bf16* buf) {
    __bf16* As = buf;
    __bf16* Bs = buf + 4096;
    load_lds16(Ag + k0, As + (wid * 32) * 32);
    load_lds16(Ag + (size_t)16 * lda + k0, As + (wid * 32 + 16) * 32);
    load_lds16(Bg + k0, Bs + (wid * BROWS) * 32);
    if (BN == 128)
      load_lds16(Bg + (size_t)16 * K + k0, Bs + (wid * BROWS + 16) * 32);
  };

  f32x4 acc[4][JN] = {};
  const int q = lane >> 4, mr = lane & 15;
  const int rkey = (mr >> 1) & 3;
  const int nst = K >> 5;
  __bf16* b0 = Sm;
  __bf16* b1 = Sm + SSTEP;
  __bf16* b2 = Sm + 2 * SSTEP;
  __bf16* b3 = (DEPTH == 4) ? Sm + 3 * SSTEP : nullptr;
  stage(0, b0);
  stage(32, b1);
  if constexpr (DEPTH == 4) stage(64, b2);
  asm volatile("s_waitcnt vmcnt(%0)" ::"n"((AH - 1) * LPS) : "memory");
  __builtin_amdgcn_s_barrier();
  for (int k = 0; k < nst; ++k) {
    if (k + AH < nst) {
      if constexpr (DEPTH == 4) stage((k + AH) << 5, b3);
      else stage((k + AH) << 5, b2);
    }
    bf16x8 af[4], bfr[JN];
#pragma unroll
    for (int i = 0; i < 4; ++i)
      af[i] = *(const bf16x8*)(b0 + (wm + i * 16 + mr) * 32 + (q ^ rkey) * 8);
#pragma unroll
    for (int j = 0; j < JN; ++j)
      bfr[j] =
          *(const bf16x8*)(b0 + 4096 + (wn + j * 16 + mr) * 32 + (q ^ rkey) * 8);
#pragma unroll
    for (int i = 0; i < 4; ++i)
#pragma unroll
      for (int j = 0; j < JN; ++j)
        acc[i][j] = __builtin_amdgcn_mfma_f32_16x16x32_bf16(af[i], bfr[j],
                                                            acc[i][j], 0, 0, 0);
    if (k + AH + 1 <= nst)
      asm volatile("s_waitcnt vmcnt(%0)" ::"n"((AH - 1) * LPS) : "memory");
    else if (DEPTH == 4 && k + AH == nst + 1)
      asm volatile("s_waitcnt vmcnt(%0)" ::"n"(LPS) : "memory");
    else
      asm volatile("s_waitcnt vmcnt(0)" ::: "memory");
    __builtin_amdgcn_s_barrier();
    if constexpr (DEPTH == 4) {
      __bf16* tp = b0; b0 = b1; b1 = b2; b2 = b3; b3 = tp;
    } else {
      __bf16* tp = b0; b0 = b1; b1 = b2; b2 = tp;
    }
  }
  // ---- epilogue: stage C in LDS, coalesced write-out ----
  if (OMODE == 1) {
    constexpr int PS = BN + 8;
    __bf16* Cs = Sm;
#pragma unroll
    for (int j = 0; j < JN; ++j) {
      float bscol = BIASROW ? 0.f : bias[bn + wn + j * 16 + mr];
#pragma unroll
      for (int i = 0; i < 4; ++i) {
#pragma unroll
        for (int r = 0; r < 4; ++r) {
          float v = acc[i][j][r] +
                    (BIASROW ? bias[bm + wm + i * 16 + q * 4 + r] : bscol);
          if (RELU) v = fmaxf(v, 0.f);
          Cs[(wm + i * 16 + q * 4 + r) * PS + wn + j * 16 + mr] = (__bf16)v;
        }
      }
    }
    __syncthreads();
    constexpr int lpr = BN / 8;
    constexpr int rpi = 512 / BN;
    const int rl = lane / lpr, cl = (lane % lpr) * 8;
#pragma unroll
    for (int it = 0; it < BN / 16; ++it) {
      int row = wid * 32 + it * rpi + rl;
      bf16x8 v = *(const bf16x8*)&Cs[row * PS + cl];
      *(bf16x8*)((__bf16*)Cout + (size_t)(bm + row) * ldc + bn + cl) = v;
    }
  } else {
    constexpr int PSF = BN + 4;
    float* Csf = (float*)Sm;
#pragma unroll
    for (int j = 0; j < JN; ++j) {
      float bscol = bias[bn + wn + j * 16 + mr];
#pragma unroll
      for (int i = 0; i < 4; ++i) {
#pragma unroll
        for (int r = 0; r < 4; ++r) {
          float v = acc[i][j][r] + bscol;
          if (RELU) v = fmaxf(v, 0.f);
          Csf[(wm + i * 16 + q * 4 + r) * PSF + wn + j * 16 + mr] = v;
        }
      }
    }
    __syncthreads();
    const int rl = lane >> 4, cl = (lane & 15) * 4;
#pragma unroll
    for (int it = 0; it < 8; ++it) {
      int row = wid * 32 + it * 4 + rl;
      f32x4 v = *(const f32x4*)&Csf[row * PSF + cl];
      size_t gidx = (size_t)(bm + row) * ldc + bn + cl;
      *(f32x4*)((float*)Cout + gidx) = v;
      bf16x4 vb = {(__bf16)v[0], (__bf16)v[1], (__bf16)v[2], (__bf16)v[3]};
      *(bf16x4*)(Cout2 + gidx) = vb;
    }
  }
}

// ---------------- fused ds + keys + vT GEMM (one launch, 3328 blocks) ----------------
__global__ __launch_bounds__(256) void gemm3_kernel(
    const __bf16* __restrict__ ki, const __bf16* __restrict__ ds_wt,
    const float* __restrict__ ds_b, float* __restrict__ att,
    __bf16* __restrict__ att_bf, const __bf16* __restrict__ kv_wt,
    const float* __restrict__ kvb, __bf16* __restrict__ kvs_k,
    __bf16* __restrict__ vT) {
  __shared__ __bf16 smem[24576];
  int bid = blockIdx.x;  // identity mapping (both swizzles measured worse)
  if (bid < 256) {
    gemm_core<64, 2, false, true, false, 3>(bid & 7, bid >> 3, ki, ds_wt, ds_b,
                                            att, att_bf, 256, kKP, 512, smem);
  } else if (bid < 1792) {
    int b2 = bid - 256;
    gemm_core<128, 1, false, false, false, 3>(b2 & 15, b2 >> 4, ki, kv_wt, kvb,
                                              kvs_k, nullptr, kKP, kKP, 2048,
                                              smem);
  } else {
    int b3 = bid - 1792;
    gemm_core<128, 1, false, false, true, 3>(b3 % 96, b3 / 96,
                                             kv_wt + (size_t)2048 * kKP, ki,
                                             kvb + 2048, vT, nullptr, kKP, kKP,
                                             12288, smem);
  }
}

// ------------- ln helper: y = LN(att + add); writes att f32 + attbf bf16 ----
__device__ __forceinline__ void ln_rows16(
    float* __restrict__ att, const __bf16* __restrict__ addbf,
    const float* __restrict__ g, const float* __restrict__ be,
    __bf16* __restrict__ attbf, int row0, int w, int lane) {
  const int c0 = lane * 8;
  float4 g0 = *(const float4*)(g + c0);
  float4 g1 = *(const float4*)(g + c0 + 4);
  float4 e0 = *(const float4*)(be + c0);
  float4 e1 = *(const float4*)(be + c0 + 4);
#pragma unroll
  for (int it = 0; it < 4; ++it) {
    const int row = row0 + it * 4 + w;
    const size_t base = (size_t)row * kHA + c0;
    float4 a0 = *(const float4*)(att + base);
    float4 a1 = *(const float4*)(att + base + 4);
    bf16x8 dv = *(const bf16x8*)(addbf + base);
    float x[8] = {a0.x + (float)dv[0], a0.y + (float)dv[1], a0.z + (float)dv[2],
                  a0.w + (float)dv[3], a1.x + (float)dv[4], a1.y + (float)dv[5],
                  a1.z + (float)dv[6], a1.w + (float)dv[7]};
    float s = 0.f, q = 0.f;
#pragma unroll
    for (int j = 0; j < 8; ++j) { s += x[j]; q += x[j] * x[j]; }
#pragma unroll
    for (int o = 1; o < 64; o <<= 1) {
      s += __shfl_xor(s, o);
      q += __shfl_xor(q, o);
    }
    const float mean = s * (1.f / kHA);
    const float inv = rsqrtf(q * (1.f / kHA) - mean * mean + 1e-5f);
    float y[8];
    y[0] = g0.x * (x[0] - mean) * inv + e0.x;
    y[1] = g0.y * (x[1] - mean) * inv + e0.y;
    y[2] = g0.z * (x[2] - mean) * inv + e0.z;
    y[3] = g0.w * (x[3] - mean) * inv + e0.w;
    y[4] = g1.x * (x[4] - mean) * inv + e1.x;
    y[5] = g1.y * (x[5] - mean) * inv + e1.y;
    y[6] = g1.z * (x[6] - mean) * inv + e1.z;
    y[7] = g1.w * (x[7] - mean) * inv + e1.w;
    *(float4*)(att + base) = (float4){y[0], y[1], y[2], y[3]};
    *(float4*)(att + base + 4) = (float4){y[4], y[5], y[6], y[7]};
    bf16x8 yb = {(__bf16)y[0], (__bf16)y[1], (__bf16)y[2], (__bf16)y[3],
                 (__bf16)y[4], (__bf16)y[5], (__bf16)y[6], (__bf16)y[7]};
    *(bf16x8*)(attbf + base) = yb;
  }
}

// ---- fused per-layer {ln1, ff1, ff2, ff3, ln2}: panel-scoped spin sync -----
// Grid = 256 blocks <= 256 CUs -> all co-resident (>=1 block/CU by capacity),
// spin-waits deadlock-free. Flags: count-to-8 per 128-row panel per phase.
// Release: per-thread __threadfence (drains wave stores, L2 wb) + barrier +
// agent-scope release add. Acquire: leader spin w/ agent acquire (L1/L2 inv),
// then barrier. Guideline 16 machinery for cross-XCD visibility.
__global__ __launch_bounds__(256) void layer_ff_kernel(
    float* __restrict__ att, const __bf16* __restrict__ atmp,
    const float* __restrict__ g1v, const float* __restrict__ b1v,
    const float* __restrict__ g2v, const float* __restrict__ b2v,
    const __bf16* __restrict__ Wt, const float* __restrict__ fb1,
    const float* __restrict__ fb2, const float* __restrict__ fb3,
    __bf16* __restrict__ attbf, __bf16* __restrict__ f1,
    __bf16* __restrict__ f2, __bf16* __restrict__ f3,
    int* __restrict__ flags, int skip_ln2) {
  __shared__ __bf16 smem[24576];
  const int id = blockIdx.x;
  const int tid = threadIdx.x;
  const int w = tid >> 6, lane = tid & 63;
  const int panel = id >> 3, bx = id & 7;

  auto release = [&](int phase) {
    __threadfence();
    __syncthreads();
    if (tid == 0)
      __hip_atomic_fetch_add(&flags[phase * 32 + panel], 1, __ATOMIC_RELEASE,
                             __HIP_MEMORY_SCOPE_AGENT);
  };
  auto acquire = [&](int phase) {
    if (tid == 0)
      while (__hip_atomic_load(&flags[phase * 32 + panel], __ATOMIC_ACQUIRE,
                               __HIP_MEMORY_SCOPE_AGENT) < 8)
        __builtin_amdgcn_s_sleep(2);
    __syncthreads();
  };

  // phase 0: ln1 on rows [id*16, +16)
  ln_rows16(att, atmp, g1v, b1v, attbf, id * 16, w, lane);
  release(0);
  // phase 1: ff1 = relu(attbf @ W1 + b1)
  acquire(0);
  gemm_core<64, 1, true, false, false, 4>(bx, panel, attbf, Wt, fb1, f1,
                                          nullptr, 512, 512, 512, smem);
  release(1);
  // phase 2: ff2 = relu(f1 @ W2 + b2)
  acquire(1);
  gemm_core<64, 1, true, false, false, 4>(bx, panel, f1, Wt + 262144, fb2, f2,
                                          nullptr, 512, 512, 512, smem);
  release(2);
  // phase 3: ff3 = f2 @ W3 + b3
  acquire(2);
  gemm_core<64, 1, false, false, false, 4>(bx, panel, f2, Wt + 524288, fb3, f3,
                                           nullptr, 512, 512, 512, smem);
  release(3);
  // phase 4: ln2 on rows [id*16, +16)  (skipped for last layer -> de_loss)
  if (!skip_ln2) {
    acquire(3);
    ln_rows16(att, f3, g2v, b2v, attbf, id * 16, w, lane);
  }
}

// ---------------- MFMA flash attention (S^T variant, reg-prefetched) --------
__global__ __launch_bounds__(256) void attn_mfma_kernel(
    const __bf16* __restrict__ attbf, const __bf16* __restrict__ kvs_k,
    const __bf16* __restrict__ vT, __bf16* __restrict__ outbf, int l) {
  const int id = blockIdx.x;
  const int kk = id >> 3;
  const int b = ((kk >> 5) << 3) | (id & 7);
  const int qt = kk & 3;
  const int h = (kk >> 2) & 7;
  __shared__ __bf16 Ks[64 * 72];
  __shared__ __bf16 Vt[64 * 72];
  __shared__ __bf16 Ps[64 * 72];
  const int t = threadIdx.x;
  const int w = t >> 6, lane = t & 63;
  const int quad = lane >> 4, mr = lane & 15;
  bf16x8 aq[2];
  {
    const __bf16* qp = attbf + ((size_t)(b * kNV + qt * 64 + w * 16 + mr) * kHA +
                                h * kA + quad * 8);
    aq[0] = *(const bf16x8*)qp;
    aq[1] = *(const bf16x8*)(qp + 32);
  }
  f32x4 o[4] = {};
  float m_ = -1e30f, l_ = 0.f;
  const int cmax = kNH + qt * 64;
  const int pr = t >> 2, pc = t & 3;
  const __bf16* kbase = kvs_k + ((size_t)(b * kW + pr) * 2048 + l * 512 + h * kA);
  const __bf16* vbase = vT + (size_t)(l * 512 + h * kA + pr) * 12288 + b * kW;
  bf16x8 kc0, kc1, vc0, vc1;
  kc0 = *(const bf16x8*)(kbase + pc * 8);
  kc1 = *(const bf16x8*)(kbase + pc * 8 + 32);
  vc0 = *(const bf16x8*)(vbase + pc * 16);
  vc1 = *(const bf16x8*)(vbase + pc * 16 + 8);
  for (int c0 = 0; c0 <= cmax; c0 += 64) {
    __syncthreads();
    *(bf16x8*)&Ks[pr * 72 + pc * 8] = kc0;
    *(bf16x8*)&Ks[pr * 72 + pc * 8 + 32] = kc1;
    *(bf16x8*)&Vt[pr * 72 + pc * 16] = vc0;
    *(bf16x8*)&Vt[pr * 72 + pc * 16 + 8] = vc1;
    __syncthreads();
    if (c0 + 64 <= cmax) {
      const __bf16* kp = kbase + (size_t)(c0 + 64) * 2048;
      const __bf16* vp = vbase + c0 + 64;
      kc0 = *(const bf16x8*)(kp + pc * 8);
      kc1 = *(const bf16x8*)(kp + pc * 8 + 32);
      vc0 = *(const bf16x8*)(vp + pc * 16);
      vc1 = *(const bf16x8*)(vp + pc * 16 + 8);
    }
    // ---- S^T = K·Q^T ----
    f32x4 s[4];
#pragma unroll
    for (int j = 0; j < 4; ++j) {
      bf16x8 ak0 = *(const bf16x8*)&Ks[(j * 16 + mr) * 72 + quad * 8];
      bf16x8 ak1 = *(const bf16x8*)&Ks[(j * 16 + mr) * 72 + quad * 8 + 32];
      f32x4 z = {};
      z = __builtin_amdgcn_mfma_f32_16x16x32_bf16(ak0, aq[0], z, 0, 0, 0);
      z = __builtin_amdgcn_mfma_f32_16x16x32_bf16(ak1, aq[1], z, 0, 0, 0);
      s[j] = z;
    }
    const int lim = cmax - c0;
    float sv[16], mx = -1e30f;
#pragma unroll
    for (int j = 0; j < 4; ++j)
#pragma unroll
      for (int r = 0; r < 4; ++r) {
        int p = j * 16 + quad * 4 + r;
        float x = (p < lim + mr) ? s[j][r] * 0.125f : -1e30f;
        sv[j * 4 + r] = x;
        mx = fmaxf(mx, x);
      }
    mx = fmaxf(mx, __shfl_xor(mx, 16));
    mx = fmaxf(mx, __shfl_xor(mx, 32));
    float mnew = fmaxf(m_, mx);
    float corr = __expf(m_ - mnew);
    float rs = 0.f;
#pragma unroll
    for (int i = 0; i < 16; ++i) {
      sv[i] = __expf(sv[i] - mnew);
      rs += sv[i];
    }
    rs += __shfl_xor(rs, 16);
    rs += __shfl_xor(rs, 32);
    l_ = l_ * corr + rs;
    m_ = mnew;
#pragma unroll
    for (int j = 0; j < 4; ++j) {
      bf16x4 pk = {(__bf16)sv[j * 4 + 0], (__bf16)sv[j * 4 + 1],
                   (__bf16)sv[j * 4 + 2], (__bf16)sv[j * 4 + 3]};
      *(bf16x4*)&Ps[(w * 16 + mr) * 72 + j * 16 + quad * 4] = pk;
    }
#pragma unroll
    for (int r = 0; r < 4; ++r) {
      float cr = __shfl(corr, quad * 4 + r);
#pragma unroll
      for (int j = 0; j < 4; ++j) o[j][r] *= cr;
    }
    bf16x8 ap0 = *(const bf16x8*)&Ps[(w * 16 + mr) * 72 + quad * 8];
    bf16x8 ap1 = *(const bf16x8*)&Ps[(w * 16 + mr) * 72 + quad * 8 + 32];
#pragma unroll
    for (int j = 0; j < 4; ++j) {
      bf16x8 b0 = *(const bf16x8*)&Vt[(j * 16 + mr) * 72 + quad * 8];
      bf16x8 b1 = *(const bf16x8*)&Vt[(j * 16 + mr) * 72 + quad * 8 + 32];
      o[j] = __builtin_amdgcn_mfma_f32_16x16x32_bf16(ap0, b0, o[j], 0, 0, 0);
      o[j] = __builtin_amdgcn_mfma_f32_16x16x32_bf16(ap1, b1, o[j], 0, 0, 0);
    }
  }
  float invl = 1.f / l_;
#pragma unroll
  for (int r = 0; r < 4; ++r) {
    float ir = __shfl(invl, quad * 4 + r);
    int row = b * kNV + qt * 64 + w * 16 + quad * 4 + r;
#pragma unroll
    for (int j = 0; j < 4; ++j)
      outbf[(size_t)row * kHA + h * kA + j * 16 + mr] = (__bf16)(o[j][r] * ir);
  }
}

// ------- fused LN2(l=3) + de-projection + loss (atomic into out) ------------
__global__ __launch_bounds__(256) void de_loss_kernel(
    const float* __restrict__ att, const __bf16* __restrict__ fbf,
    const float* __restrict__ g2, const float* __restrict__ b2,
    const __bf16* __restrict__ de_wt, const float* __restrict__ de_b,
    const float* __restrict__ pred_u, float* __restrict__ out) {
  __shared__ __bf16 Als[64 * 512];  // 64 KB, row-XOR swizzled
  __shared__ float red[4];
  const int blk = blockIdx.x;
  const int t = threadIdx.x;
  const int w = t >> 6, lane = t & 63, quad = lane >> 4, mr = lane & 15;
  // ---- phase A: LN2 into LDS ----
  {
    const int c0 = lane * 8;
    float4 ga = *(const float4*)(g2 + c0);
    float4 gb = *(const float4*)(g2 + c0 + 4);
    float4 ba = *(const float4*)(b2 + c0);
    float4 bb = *(const float4*)(b2 + c0 + 4);
    for (int rr = 0; rr < 16; ++rr) {
      const int lrow = w * 16 + rr;
      const size_t base = (size_t)(blk * 64 + lrow) * 512 + c0;
      float4 a0 = *(const float4*)(att + base);
      float4 a1 = *(const float4*)(att + base + 4);
      bf16x8 dv = *(const bf16x8*)(fbf + base);
      float x[8] = {a0.x + (float)dv[0], a0.y + (float)dv[1],
                    a0.z + (float)dv[2], a0.w + (float)dv[3],
                    a1.x + (float)dv[4], a1.y + (float)dv[5],
                    a1.z + (float)dv[6], a1.w + (float)dv[7]};
      float s = 0.f, q = 0.f;
#pragma unroll
      for (int j = 0; j < 8; ++j) { s += x[j]; q += x[j] * x[j]; }
#pragma unroll
      for (int o = 1; o < 64; o <<= 1) {
        s += __shfl_xor(s, o);
        q += __shfl_xor(q, o);
      }
      const float mean = s * (1.f / kHA);
      const float inv = rsqrtf(q * (1.f / kHA) - mean * mean + 1e-5f);
      bf16x8 yv = {(__bf16)(ga.x * (x[0] - mean) * inv + ba.x),
                   (__bf16)(ga.y * (x[1] - mean) * inv + ba.y),
                   (__bf16)(ga.z * (x[2] - mean) * inv + ba.z),
                   (__bf16)(ga.w * (x[3] - mean) * inv + ba.w),
                   (__bf16)(gb.x * (x[4] - mean) * inv + bb.x),
                   (__bf16)(gb.y * (x[5] - mean) * inv + bb.y),
                   (__bf16)(gb.z * (x[6] - mean) * inv + bb.z),
                   (__bf16)(gb.w * (x[7] - mean) * inv + bb.w)};
      *(bf16x8*)&Als[lrow * 512 + ((lane ^ (lrow & 7)) << 3)] = yv;
    }
  }
  __syncthreads();
  // ---- MFMA K-loop (A from LDS) ----
  const int row0 = blk * 64 + w * 16;
  const int lrowA = w * 16 + mr;
  f32x4 acc[8] = {};
#pragma unroll 4
  for (int k0 = 0; k0 < 512; k0 += 32) {
    const int grp = (((k0 >> 3) + quad) ^ (lrowA & 7)) << 3;
    bf16x8 a = *(const bf16x8*)&Als[lrowA * 512 + grp];
#pragma unroll
    for (int j = 0; j < 8; ++j) {
      bf16x8 bb =
          *(const bf16x8*)(de_wt + (size_t)(j * 16 + mr) * 512 + k0 + quad * 8);
      acc[j] = __builtin_amdgcn_mfma_f32_16x16x32_bf16(a, bb, acc[j], 0, 0, 0);
    }
  }
  float dbv[8];
#pragma unroll
  for (int j = 0; j < 8; ++j) dbv[j] = de_b[j * 16 + mr];
  float lpacc = 0.f;
#pragma unroll
  for (int r = 0; r < 4; ++r) {
    int row = row0 + quad * 4 + r;
    int v = row & 255;
    float lg[8], mx = -1e30f;
#pragma unroll
    for (int j = 0; j < 8; ++j) {
      lg[j] = acc[j][r] + dbv[j];
      mx = fmaxf(mx, lg[j]);
    }
    mx = fmaxf(mx, __shfl_xor(mx, 1));
    mx = fmaxf(mx, __shfl_xor(mx, 2));
    mx = fmaxf(mx, __shfl_xor(mx, 4));
    mx = fmaxf(mx, __shfl_xor(mx, 8));
    float se = 0.f;
#pragma unroll
    for (int j = 0; j < 8; ++j) se += __expf(lg[j] - mx);
    se += __shfl_xor(se, 1);
    se += __shfl_xor(se, 2);
    se += __shfl_xor(se, 4);
    se += __shfl_xor(se, 8);
    float lse = mx + __logf(se);
    float u = pred_u[(row >> 8) * 256 + v];
    int tgt = (int)floorf(u * 128.f);
    tgt = max(0, min(127, tgt));
    float cand = (mr == (tgt & 15)) ? lg[tgt >> 4] : 0.f;
    cand += __shfl_xor(cand, 1);
    cand += __shfl_xor(cand, 2);
    cand += __shfl_xor(cand, 4);
    cand += __shfl_xor(cand, 8);
    float lp = (v >= 1) ? (4.8520302639196171f + cand - lse) : 0.f;  // ln(128)
    lpacc += lp;
  }
  lpacc += __shfl_xor(lpacc, 16);
  lpacc += __shfl_xor(lpacc, 32);
  if (lane == 0) red[w] = lpacc;
  __syncthreads();
  if (t == 0)
    atomicAdd(&out[blk >> 2], -(red[0] + red[1] + red[2] + red[3]));
}

extern "C" void kernel_launch(void* const* d_in, const int* in_sizes, int n_in,
                              void* d_out, int out_size, void* d_ws, size_t ws_size,
                              hipStream_t stream) {
  const float* hist   = (const float*)d_in[0];
  const float* hist_u = (const float*)d_in[1];
  const float* pred   = (const float*)d_in[2];
  const float* pred_u = (const float*)d_in[3];
  const float* ds_w   = (const float*)d_in[4];
  const float* ds_b   = (const float*)d_in[5];
  const float* key_w  = (const float*)d_in[6];
  const float* key_b  = (const float*)d_in[7];
  const float* val_w  = (const float*)d_in[8];
  const float* val_b  = (const float*)d_in[9];
  const float* ln1_g  = (const float*)d_in[10];
  const float* ln1_b  = (const float*)d_in[11];
  const float* ln2_g  = (const float*)d_in[12];
  const float* ln2_b  = (const float*)d_in[13];
  const float* ff_w1  = (const float*)d_in[14];
  const float* ff_b1  = (const float*)d_in[15];
  const float* ff_w2  = (const float*)d_in[16];
  const float* ff_b2  = (const float*)d_in[17];
  const float* ff_w3  = (const float*)d_in[18];
  const float* ff_b3  = (const float*)d_in[19];
  const float* de_w   = (const float*)d_in[20];
  const float* de_b   = (const float*)d_in[21];
  float* out = (float*)d_out;

  char* ws = (char*)d_ws;
  size_t off = 0;
  auto alloc = [&](size_t bytes) { char* p = ws + off; off += bytes; return p; };
  __bf16* ki_bf  = (__bf16*)alloc((size_t)kB * kW * kKP * 2);       // 7.1 MB
  __bf16* kv_wt  = (__bf16*)alloc((size_t)4096 * kKP * 2);          // 2.4 MB
  __bf16* ffw_t  = (__bf16*)alloc((size_t)12 * 512 * 512 * 2);      // 6.3 MB
  __bf16* ds_wt  = (__bf16*)alloc((size_t)512 * 256 * 2);
  __bf16* de_wt  = (__bf16*)alloc((size_t)128 * 512 * 2);
  float*  kvb    = (float*)alloc((size_t)4096 * 4);
  __bf16* kvs_k  = (__bf16*)alloc((size_t)kB * kW * 2048 * 2);      // 50.3 MB
  __bf16* vT     = (__bf16*)alloc((size_t)2048 * 12288 * 2);        // 50.3 MB
  float*  att    = (float*)alloc((size_t)kRows * kHA * 4);          // 8.4 MB
  __bf16* att_bf = (__bf16*)alloc((size_t)kRows * kHA * 2);
  __bf16* tmp_bf = (__bf16*)alloc((size_t)kRows * kHA * 2);
  __bf16* ff1_bf = (__bf16*)alloc((size_t)kRows * kM * 2);
  __bf16* ff2_bf = (__bf16*)alloc((size_t)kRows * kM * 2);
  int*    flags  = (int*)alloc((size_t)512 * 4);  // 4 layers x 4 phases x 32

  prep_kernel<<<kPrepBlocks, 256, 0, stream>>>(
      hist, hist_u, pred, pred_u, key_w, val_w, ff_w1, ff_w2, ff_w3, ds_w, de_w,
      key_b, val_b, ki_bf, kv_wt, ffw_t, ds_wt, de_wt, kvb, out, flags);

  // ds + keys + vT in one launch
  gemm3_kernel<<<3328, 256, 0, stream>>>(ki_bf, ds_wt, ds_b, att, att_bf, kv_wt,
                                         kvb, kvs_k, vT);

  for (int l = 0; l < kL; ++l) {
    attn_mfma_kernel<<<512, 256, 0, stream>>>(att_bf, kvs_k, vT, tmp_bf, l);
    layer_ff_kernel<<<256, 256, 0, stream>>>(
        att, tmp_bf, ln1_g + l * kHA, ln1_b + l * kHA, ln2_g + l * kHA,
        ln2_b + l * kHA, ffw_t + (size_t)(l * 3) * 262144, ff_b1 + l * kM,
        ff_b2 + l * kM, ff_b3 + l * kHA, att_bf, ff1_bf, ff2_bf, tmp_bf,
        flags + l * 128, l == kL - 1);
  }
  // final LN2 fused into de_loss (att holds LN1-out y of layer 3; tmp_bf = ff3)
  de_loss_kernel<<<64, 256, 0, stream>>>(att, tmp_bf, ln2_g + 3 * kHA,
                                         ln2_b + 3 * kHA, de_wt, de_b, pred_u,
                                         out);
}

// Round 11
// 445.429 us; speedup vs baseline: 2.2786x; 2.2786x over previous
//
#include <hip/hip_runtime.h>

// Problem constants (AttentionalCopula)
constexpr int kB = 16, kD = 256, kNH = 512, kNV = 256, kW = 768;
constexpr int kL = 4, kH = 8, kA = 64, kHA = 512, kM = 512, kR = 128;
constexpr int kKP = 288;  // K=257 zero-padded to multiple of 32
constexpr int kRows = kB * kNV;  // 4096

typedef __bf16 bf16x8 __attribute__((ext_vector_type(8)));
typedef __bf16 bf16x4 __attribute__((ext_vector_type(4)));
typedef float f32x4 __attribute__((ext_vector_type(4)));

__device__ inline void load_lds16(const __bf16* g, __bf16* l) {
  __builtin_amdgcn_global_load_lds(
      (const __attribute__((address_space(1))) void*)g,
      (__attribute__((address_space(3))) void*)l, 16, 0, 0);
}

// ---------------- merged prep kernel (1 launch, block-range sections) --------
constexpr int kP1 = kB * kW * kKP;  // 3,538,944 -> 13824 blocks
constexpr int kPrepBlocks = 17681;

__global__ void prep_kernel(const float* __restrict__ hist,
                            const float* __restrict__ hist_u,
                            const float* __restrict__ pred,
                            const float* __restrict__ pred_u,
                            const float* __restrict__ kw,
                            const float* __restrict__ vw,
                            const float* __restrict__ w1,
                            const float* __restrict__ w2,
                            const float* __restrict__ w3,
                            const float* __restrict__ ds_w,
                            const float* __restrict__ de_w,
                            const float* __restrict__ key_b,
                            const float* __restrict__ val_b,
                            __bf16* __restrict__ ki,
                            __bf16* __restrict__ kvwt,
                            __bf16* __restrict__ ffwt,
                            __bf16* __restrict__ ds_wt,
                            __bf16* __restrict__ de_wt,
                            float* __restrict__ kvb,
                            float* __restrict__ outz) {
  __shared__ float ld[2080];  // 32x65 (B) / 32x33 (C,D,E)
  const int bid = blockIdx.x;
  const int t = threadIdx.x;
  if (bid < 13824) {
    // ---- A: ki fill ----
    int i = bid * 256 + t;
    int d = i % kKP;
    int bw = i / kKP;
    int w = bw % kW;
    int b = bw / kW;
    float v = 0.f;
    if (d < 257) {
      if (w < kNH)
        v = (d < kD) ? hist[((size_t)b * kNH + w) * kD + d] : hist_u[b * kNH + w];
      else {
        int p = w - kNH;
        v = (d < kD) ? pred[((size_t)b * kNV + p) * kD + d] : pred_u[b * kNV + p];
      }
    }
    ki[i] = (__bf16)v;
  } else if (bid < 14400) {
    // ---- B: kv weight transpose ----
    int bb = bid - 13824;
    bool isv = bb >= 288;
    int rem = isv ? bb - 288 : bb;
    int pair = rem / 9;
    int dt = rem - pair * 9;
    int d0 = dt * 32;
    const float* src = (isv ? vw : kw) + (size_t)pair * 257 * 64;
    int a = t & 63, dg = t >> 6;
#pragma unroll
    for (int ii = 0; ii < 8; ++ii) {
      int d = d0 + dg * 8 + ii;
      ld[(dg * 8 + ii) * 65 + a] = (d < 257) ? src[(size_t)d * 64 + a] : 0.f;
    }
    __syncthreads();
    int r = t >> 2, seg = t & 3;
    bf16x8 v;
#pragma unroll
    for (int j = 0; j < 8; ++j) v[j] = (__bf16)ld[(seg * 8 + j) * 65 + r];
    *(bf16x8*)&kvwt[((size_t)(isv ? 2048 : 0) + pair * 64 + r) * 288 + d0 +
                    seg * 8] = v;
  } else if (bid < 17472) {
    // ---- C: ff weight transpose ----
    int cc = bid - 14400;
    int mat = cc >> 8;
    int tile = cc & 255;
    int n0 = (tile & 15) * 32, k0 = (tile >> 4) * 32;
    int l = mat / 3, which = mat - l * 3;
    const float* src = (which == 0 ? w1 : which == 1 ? w2 : w3) +
                       (size_t)l * 262144;
    int col = t & 31, kr = t >> 5;
#pragma unroll
    for (int p = 0; p < 4; ++p)
      ld[(kr + p * 8) * 33 + col] = src[(size_t)(k0 + kr + p * 8) * 512 + n0 + col];
    __syncthreads();
    int nr = t >> 3, seg = t & 7;
    bf16x4 v;
#pragma unroll
    for (int j = 0; j < 4; ++j) v[j] = (__bf16)ld[(seg * 4 + j) * 33 + nr];
    *(bf16x4*)&ffwt[(size_t)mat * 262144 + (n0 + nr) * 512 + k0 + seg * 4] = v;
  } else if (bid < 17600) {
    // ---- D: ds_w transpose ----
    int cc = bid - 17472;
    int n0 = (cc & 15) * 32, k0 = (cc >> 4) * 32;
    int col = t & 31, kr = t >> 5;
#pragma unroll
    for (int p = 0; p < 4; ++p)
      ld[(kr + p * 8) * 33 + col] = ds_w[(size_t)(k0 + kr + p * 8) * 512 + n0 + col];
    __syncthreads();
    int nr = t >> 3, seg = t & 7;
    bf16x4 v;
#pragma unroll
    for (int j = 0; j < 4; ++j) v[j] = (__bf16)ld[(seg * 4 + j) * 33 + nr];
    *(bf16x4*)&ds_wt[(n0 + nr) * 256 + k0 + seg * 4] = v;
  } else if (bid < 17664) {
    // ---- E: de_w transpose ----
    int cc = bid - 17600;
    int n0 = (cc & 3) * 32, k0 = (cc >> 2) * 32;
    int col = t & 31, kr = t >> 5;
#pragma unroll
    for (int p = 0; p < 4; ++p)
      ld[(kr + p * 8) * 33 + col] = de_w[(size_t)(k0 + kr + p * 8) * 128 + n0 + col];
    __syncthreads();
    int nr = t >> 3, seg = t & 7;
    bf16x4 v;
#pragma unroll
    for (int j = 0; j < 4; ++j) v[j] = (__bf16)ld[(seg * 4 + j) * 33 + nr];
    *(bf16x4*)&de_wt[(n0 + nr) * 512 + k0 + seg * 4] = v;
  } else {
    // ---- F: kvb + out zero ----
    int j = (bid - 17664) * 256 + t;
    if (j < 4096) {
      bool isv = j >= 2048;
      int cc = isv ? j - 2048 : j;
      int l = cc >> 9, rest = cc & 511;
      kvb[j] = isv ? val_b[l * 512 + rest] : key_b[l * 512 + rest];
    } else if (j < 4112) {
      outz[j - 4096] = 0.f;
    }
  }
}

// ---- generic bf16 MFMA GEMM core (DEPTH-buffer counted-vmcnt pipeline) ------
template <int BN, int OMODE, bool RELU, bool KIMAP, bool BIASROW, int DEPTH>
__device__ __forceinline__ void gemm_core(
    int bxv, int byv, const __bf16* __restrict__ A,
    const __bf16* __restrict__ Bt, const float* __restrict__ bias,
    void* __restrict__ Cout, __bf16* __restrict__ Cout2, int K, int lda,
    int ldc, __bf16* Sm) {
  constexpr int JN = BN / 32;
  constexpr int BROWS = BN / 4;
  constexpr int SSTEP = (128 + BN) * 32;
  constexpr int LPS = (BN == 128) ? 4 : 3;
  constexpr int AH = DEPTH - 1;
  const int t = threadIdx.x;
  const int wid = t >> 6;
  const int lane = t & 63;
  const int bm = byv * 128;
  const int bn = bxv * BN;
  const int wm = (wid >> 1) * 64;
  const int wn = (wid & 1) * (BN / 2);
  const int sr = lane >> 2, sc = lane & 3;
  const int skey = (sr >> 1) & 3;
  const int abase = KIMAP ? ((bm >> 8) * 768 + 512 + (bm & 255)) : bm;
  const __bf16* Ag = A + (size_t)(abase + wid * 32 + sr) * lda + (sc ^ skey) * 8;
  const __bf16* Bg = Bt + (size_t)(bn + wid * BROWS + sr) * K + (sc ^ skey) * 8;

  auto stage = [&](int k0, __bf16* buf) {
    __bf16* As = buf;
    __bf16* Bs = buf + 4096;
    load_lds16(Ag + k0, As + (wid * 32) * 32);
    load_lds16(Ag + (size_t)16 * lda + k0, As + (wid * 32 + 16) * 32);
    load_lds16(Bg + k0, Bs + (wid * BROWS) * 32);
    if (BN == 128)
      load_lds16(Bg + (size_t)16 * K + k0, Bs + (wid * BROWS + 16) * 32);
  };

  f32x4 acc[4][JN] = {};
  const int q = lane >> 4, mr = lane & 15;
  const int rkey = (mr >> 1) & 3;
  const int nst = K >> 5;
  __bf16* b0 = Sm;
  __bf16* b1 = Sm + SSTEP;
  __bf16* b2 = Sm + 2 * SSTEP;
  __bf16* b3 = (DEPTH == 4) ? Sm + 3 * SSTEP : nullptr;
  stage(0, b0);
  stage(32, b1);
  if constexpr (DEPTH == 4) stage(64, b2);
  asm volatile("s_waitcnt vmcnt(%0)" ::"n"((AH - 1) * LPS) : "memory");
  __builtin_amdgcn_s_barrier();
  for (int k = 0; k < nst; ++k) {
    if (k + AH < nst) {
      if constexpr (DEPTH == 4) stage((k + AH) << 5, b3);
      else stage((k + AH) << 5, b2);
    }
    bf16x8 af[4], bfr[JN];
#pragma unroll
    for (int i = 0; i < 4; ++i)
      af[i] = *(const bf16x8*)(b0 + (wm + i * 16 + mr) * 32 + (q ^ rkey) * 8);
#pragma unroll
    for (int j = 0; j < JN; ++j)
      bfr[j] =
          *(const bf16x8*)(b0 + 4096 + (wn + j * 16 + mr) * 32 + (q ^ rkey) * 8);
#pragma unroll
    for (int i = 0; i < 4; ++i)
#pragma unroll
      for (int j = 0; j < JN; ++j)
        acc[i][j] = __builtin_amdgcn_mfma_f32_16x16x32_bf16(af[i], bfr[j],
                                                            acc[i][j], 0, 0, 0);
    if (k + AH + 1 <= nst)
      asm volatile("s_waitcnt vmcnt(%0)" ::"n"((AH - 1) * LPS) : "memory");
    else if (DEPTH == 4 && k + AH == nst + 1)
      asm volatile("s_waitcnt vmcnt(%0)" ::"n"(LPS) : "memory");
    else
      asm volatile("s_waitcnt vmcnt(0)" ::: "memory");
    __builtin_amdgcn_s_barrier();
    if constexpr (DEPTH == 4) {
      __bf16* tp = b0; b0 = b1; b1 = b2; b2 = b3; b3 = tp;
    } else {
      __bf16* tp = b0; b0 = b1; b1 = b2; b2 = tp;
    }
  }
  // ---- epilogue: stage C in LDS, coalesced write-out ----
  if (OMODE == 1) {
    constexpr int PS = BN + 8;
    __bf16* Cs = Sm;
#pragma unroll
    for (int j = 0; j < JN; ++j) {
      float bscol = BIASROW ? 0.f : bias[bn + wn + j * 16 + mr];
#pragma unroll
      for (int i = 0; i < 4; ++i) {
#pragma unroll
        for (int r = 0; r < 4; ++r) {
          float v = acc[i][j][r] +
                    (BIASROW ? bias[bm + wm + i * 16 + q * 4 + r] : bscol);
          if (RELU) v = fmaxf(v, 0.f);
          Cs[(wm + i * 16 + q * 4 + r) * PS + wn + j * 16 + mr] = (__bf16)v;
        }
      }
    }
    __syncthreads();
    constexpr int lpr = BN / 8;
    constexpr int rpi = 512 / BN;
    const int rl = lane / lpr, cl = (lane % lpr) * 8;
#pragma unroll
    for (int it = 0; it < BN / 16; ++it) {
      int row = wid * 32 + it * rpi + rl;
      bf16x8 v = *(const bf16x8*)&Cs[row * PS + cl];
      *(bf16x8*)((__bf16*)Cout + (size_t)(bm + row) * ldc + bn + cl) = v;
    }
  } else {
    constexpr int PSF = BN + 4;
    float* Csf = (float*)Sm;
#pragma unroll
    for (int j = 0; j < JN; ++j) {
      float bscol = bias[bn + wn + j * 16 + mr];
#pragma unroll
      for (int i = 0; i < 4; ++i) {
#pragma unroll
        for (int r = 0; r < 4; ++r) {
          float v = acc[i][j][r] + bscol;
          if (RELU) v = fmaxf(v, 0.f);
          Csf[(wm + i * 16 + q * 4 + r) * PSF + wn + j * 16 + mr] = v;
        }
      }
    }
    __syncthreads();
    const int rl = lane >> 4, cl = (lane & 15) * 4;
#pragma unroll
    for (int it = 0; it < 8; ++it) {
      int row = wid * 32 + it * 4 + rl;
      f32x4 v = *(const f32x4*)&Csf[row * PSF + cl];
      size_t gidx = (size_t)(bm + row) * ldc + bn + cl;
      *(f32x4*)((float*)Cout + gidx) = v;
      bf16x4 vb = {(__bf16)v[0], (__bf16)v[1], (__bf16)v[2], (__bf16)v[3]};
      *(bf16x4*)(Cout2 + gidx) = vb;
    }
  }
}

// ---------------- fused ds + keys + vT GEMM (one launch, 3328 blocks) ----------------
__global__ __launch_bounds__(256) void gemm3_kernel(
    const __bf16* __restrict__ ki, const __bf16* __restrict__ ds_wt,
    const float* __restrict__ ds_b, float* __restrict__ att,
    __bf16* __restrict__ att_bf, const __bf16* __restrict__ kv_wt,
    const float* __restrict__ kvb, __bf16* __restrict__ kvs_k,
    __bf16* __restrict__ vT) {
  __shared__ __bf16 smem[24576];
  int bid = blockIdx.x;  // identity mapping (both swizzles measured worse)
  if (bid < 256) {
    gemm_core<64, 2, false, true, false, 3>(bid & 7, bid >> 3, ki, ds_wt, ds_b,
                                            att, att_bf, 256, kKP, 512, smem);
  } else if (bid < 1792) {
    int b2 = bid - 256;
    gemm_core<128, 1, false, false, false, 3>(b2 & 15, b2 >> 4, ki, kv_wt, kvb,
                                              kvs_k, nullptr, kKP, kKP, 2048,
                                              smem);
  } else {
    int b3 = bid - 1792;
    gemm_core<128, 1, false, false, true, 3>(b3 % 96, b3 / 96,
                                             kv_wt + (size_t)2048 * kKP, ki,
                                             kvb + 2048, vT, nullptr, kKP, kKP,
                                             12288, smem);
  }
}

// ---------------- ff2/ff3 GEMMs (gemm_core wrappers, 4-deep pipeline) -------
template <bool RELU>
__global__ __launch_bounds__(256) void gemm_ff_kernel(
    const __bf16* __restrict__ A, const __bf16* __restrict__ Bt,
    const float* __restrict__ bias, __bf16* __restrict__ Cout) {
  __shared__ __bf16 smem[24576];
  gemm_core<64, 1, RELU, false, false, 4>(blockIdx.x, blockIdx.y, A, Bt, bias,
                                          Cout, nullptr, 512, 512, 512, smem);
}

// ---- fused LN1 + ff1: block owns 64 COMPLETE rows x 128 cols ---------------
// Phase A: y = LN1(att + atmp) into swizzled LDS A-tile (de_loss pattern);
// bx==0 blocks also write y -> y32 (f32, consumed later by ln2/de_loss).
// Phase B: f1 = relu(y @ W1 + b1), A from LDS, B 3-buf counted-vmcnt.
__global__ __launch_bounds__(256) void ff1_fused_kernel(
    const float* __restrict__ att, const __bf16* __restrict__ atmp,
    const float* __restrict__ g1, const float* __restrict__ b1g,
    const __bf16* __restrict__ Wt, const float* __restrict__ fb1,
    float* __restrict__ y32, __bf16* __restrict__ f1) {
  __shared__ __bf16 Als[64 * 512];  // 64 KB, row-XOR swizzled
  __shared__ __bf16 Bsm[3 * 4096];  // 24 KB: B staging (3-buf) / C epilogue
  const int id = blockIdx.x;
  const int rg = id >> 2, bx = id & 3;
  const int tid = threadIdx.x;
  const int w = tid >> 6, lane = tid & 63;
  const int quad = lane >> 4, mr = lane & 15;
  // ---- phase A: LN1 for rows [rg*64, +64) ----
  {
    const int c0 = lane * 8;
    float4 ga = *(const float4*)(g1 + c0);
    float4 gb = *(const float4*)(g1 + c0 + 4);
    float4 ba = *(const float4*)(b1g + c0);
    float4 bb = *(const float4*)(b1g + c0 + 4);
    for (int it = 0; it < 16; ++it) {
      const int lrow = it * 4 + w;
      const size_t base = (size_t)(rg * 64 + lrow) * 512 + c0;
      float4 a0 = *(const float4*)(att + base);
      float4 a1 = *(const float4*)(att + base + 4);
      bf16x8 dv = *(const bf16x8*)(atmp + base);
      float x[8] = {a0.x + (float)dv[0], a0.y + (float)dv[1],
                    a0.z + (float)dv[2], a0.w + (float)dv[3],
                    a1.x + (float)dv[4], a1.y + (float)dv[5],
                    a1.z + (float)dv[6], a1.w + (float)dv[7]};
      float s = 0.f, q = 0.f;
#pragma unroll
      for (int j = 0; j < 8; ++j) { s += x[j]; q += x[j] * x[j]; }
#pragma unroll
      for (int o = 1; o < 64; o <<= 1) {
        s += __shfl_xor(s, o);
        q += __shfl_xor(q, o);
      }
      const float mean = s * (1.f / kHA);
      const float inv = rsqrtf(q * (1.f / kHA) - mean * mean + 1e-5f);
      float y[8];
      y[0] = ga.x * (x[0] - mean) * inv + ba.x;
      y[1] = ga.y * (x[1] - mean) * inv + ba.y;
      y[2] = ga.z * (x[2] - mean) * inv + ba.z;
      y[3] = ga.w * (x[3] - mean) * inv + ba.w;
      y[4] = gb.x * (x[4] - mean) * inv + bb.x;
      y[5] = gb.y * (x[5] - mean) * inv + bb.y;
      y[6] = gb.z * (x[6] - mean) * inv + bb.z;
      y[7] = gb.w * (x[7] - mean) * inv + bb.w;
      bf16x8 yv = {(__bf16)y[0], (__bf16)y[1], (__bf16)y[2], (__bf16)y[3],
                   (__bf16)y[4], (__bf16)y[5], (__bf16)y[6], (__bf16)y[7]};
      *(bf16x8*)&Als[lrow * 512 + ((lane ^ (lrow & 7)) << 3)] = yv;
      if (bx == 0) {
        *(float4*)(y32 + base) = (float4){y[0], y[1], y[2], y[3]};
        *(float4*)(y32 + base + 4) = (float4){y[4], y[5], y[6], y[7]};
      }
    }
  }
  __syncthreads();
  // ---- phase B: f1 tile [64 x 128] = relu(y @ W1 + b1) ----
  const int sr = lane >> 2, sc = lane & 3;
  const int skey = (sr >> 1) & 3;
  const __bf16* Bg =
      Wt + (size_t)(bx * 128 + w * 32 + sr) * 512 + (sc ^ skey) * 8;
  auto stageB = [&](int k0, __bf16* Bs) {
    load_lds16(Bg + k0, Bs + (w * 32) * 32);
    load_lds16(Bg + (size_t)16 * 512 + k0, Bs + (w * 32 + 16) * 32);
  };
  const int rkey = (mr >> 1) & 3;
  const int arow = w * 16 + mr;
  f32x4 acc[8] = {};
  __bf16* p0 = Bsm;
  __bf16* p1 = Bsm + 4096;
  __bf16* p2 = Bsm + 8192;
  stageB(0, p0);
  stageB(32, p1);
  asm volatile("s_waitcnt vmcnt(2)" ::: "memory");
  __builtin_amdgcn_s_barrier();
  for (int k = 0; k < 16; ++k) {
    if (k + 2 < 16) stageB((k + 2) << 5, p2);
    const int grp = (((k << 2) + quad) ^ (mr & 7)) << 3;
    bf16x8 af = *(const bf16x8*)&Als[arow * 512 + grp];
    bf16x8 bfr[8];
#pragma unroll
    for (int j = 0; j < 8; ++j)
      bfr[j] = *(const bf16x8*)(p0 + (j * 16 + mr) * 32 + (quad ^ rkey) * 8);
#pragma unroll
    for (int j = 0; j < 8; ++j)
      acc[j] = __builtin_amdgcn_mfma_f32_16x16x32_bf16(af, bfr[j], acc[j], 0,
                                                       0, 0);
    if (k + 3 <= 16)
      asm volatile("s_waitcnt vmcnt(2)" ::: "memory");
    else
      asm volatile("s_waitcnt vmcnt(0)" ::: "memory");
    __builtin_amdgcn_s_barrier();
    __bf16* tp = p0; p0 = p1; p1 = p2; p2 = tp;
  }
  // ---- epilogue: stage C in Bsm, coalesced write ----
  __bf16* Cs = Bsm;  // 64 x 136 = 8704 elems <= 12288
#pragma unroll
  for (int j = 0; j < 8; ++j) {
    float bc = fb1[bx * 128 + j * 16 + mr];
#pragma unroll
    for (int r = 0; r < 4; ++r) {
      float v = fmaxf(acc[j][r] + bc, 0.f);
      Cs[(w * 16 + quad * 4 + r) * 136 + j * 16 + mr] = (__bf16)v;
    }
  }
  __syncthreads();
#pragma unroll
  for (int p = 0; p < 4; ++p) {
    int row_l = w * 16 + p * 4 + (lane >> 4);
    int col_l = (lane & 15) * 8;
    bf16x8 v = *(const bf16x8*)&Cs[row_l * 136 + col_l];
    *(bf16x8*)&f1[(size_t)(rg * 64 + row_l) * 512 + bx * 128 + col_l] = v;
  }
}

// ---------------- MFMA flash attention (S^T variant, reg-prefetched) --------
__global__ __launch_bounds__(256) void attn_mfma_kernel(
    const __bf16* __restrict__ attbf, const __bf16* __restrict__ kvs_k,
    const __bf16* __restrict__ vT, __bf16* __restrict__ outbf, int l) {
  const int id = blockIdx.x;
  const int kk = id >> 3;
  const int b = ((kk >> 5) << 3) | (id & 7);
  const int qt = kk & 3;
  const int h = (kk >> 2) & 7;
  __shared__ __bf16 Ks[64 * 72];
  __shared__ __bf16 Vt[64 * 72];
  __shared__ __bf16 Ps[64 * 72];
  const int t = threadIdx.x;
  const int w = t >> 6, lane = t & 63;
  const int quad = lane >> 4, mr = lane & 15;
  bf16x8 aq[2];
  {
    const __bf16* qp = attbf + ((size_t)(b * kNV + qt * 64 + w * 16 + mr) * kHA +
                                h * kA + quad * 8);
    aq[0] = *(const bf16x8*)qp;
    aq[1] = *(const bf16x8*)(qp + 32);
  }
  f32x4 o[4] = {};
  float m_ = -1e30f, l_ = 0.f;
  const int cmax = kNH + qt * 64;
  const int pr = t >> 2, pc = t & 3;
  const __bf16* kbase = kvs_k + ((size_t)(b * kW + pr) * 2048 + l * 512 + h * kA);
  const __bf16* vbase = vT + (size_t)(l * 512 + h * kA + pr) * 12288 + b * kW;
  bf16x8 kc0, kc1, vc0, vc1;
  kc0 = *(const bf16x8*)(kbase + pc * 8);
  kc1 = *(const bf16x8*)(kbase + pc * 8 + 32);
  vc0 = *(const bf16x8*)(vbase + pc * 16);
  vc1 = *(const bf16x8*)(vbase + pc * 16 + 8);
  for (int c0 = 0; c0 <= cmax; c0 += 64) {
    __syncthreads();
    *(bf16x8*)&Ks[pr * 72 + pc * 8] = kc0;
    *(bf16x8*)&Ks[pr * 72 + pc * 8 + 32] = kc1;
    *(bf16x8*)&Vt[pr * 72 + pc * 16] = vc0;
    *(bf16x8*)&Vt[pr * 72 + pc * 16 + 8] = vc1;
    __syncthreads();
    if (c0 + 64 <= cmax) {
      const __bf16* kp = kbase + (size_t)(c0 + 64) * 2048;
      const __bf16* vp = vbase + c0 + 64;
      kc0 = *(const bf16x8*)(kp + pc * 8);
      kc1 = *(const bf16x8*)(kp + pc * 8 + 32);
      vc0 = *(const bf16x8*)(vp + pc * 16);
      vc1 = *(const bf16x8*)(vp + pc * 16 + 8);
    }
    // ---- S^T = K·Q^T ----
    f32x4 s[4];
#pragma unroll
    for (int j = 0; j < 4; ++j) {
      bf16x8 ak0 = *(const bf16x8*)&Ks[(j * 16 + mr) * 72 + quad * 8];
      bf16x8 ak1 = *(const bf16x8*)&Ks[(j * 16 + mr) * 72 + quad * 8 + 32];
      f32x4 z = {};
      z = __builtin_amdgcn_mfma_f32_16x16x32_bf16(ak0, aq[0], z, 0, 0, 0);
      z = __builtin_amdgcn_mfma_f32_16x16x32_bf16(ak1, aq[1], z, 0, 0, 0);
      s[j] = z;
    }
    const int lim = cmax - c0;
    float sv[16], mx = -1e30f;
#pragma unroll
    for (int j = 0; j < 4; ++j)
#pragma unroll
      for (int r = 0; r < 4; ++r) {
        int p = j * 16 + quad * 4 + r;
        float x = (p < lim + mr) ? s[j][r] * 0.125f : -1e30f;
        sv[j * 4 + r] = x;
        mx = fmaxf(mx, x);
      }
    mx = fmaxf(mx, __shfl_xor(mx, 16));
    mx = fmaxf(mx, __shfl_xor(mx, 32));
    float mnew = fmaxf(m_, mx);
    float corr = __expf(m_ - mnew);
    float rs = 0.f;
#pragma unroll
    for (int i = 0; i < 16; ++i) {
      sv[i] = __expf(sv[i] - mnew);
      rs += sv[i];
    }
    rs += __shfl_xor(rs, 16);
    rs += __shfl_xor(rs, 32);
    l_ = l_ * corr + rs;
    m_ = mnew;
#pragma unroll
    for (int j = 0; j < 4; ++j) {
      bf16x4 pk = {(__bf16)sv[j * 4 + 0], (__bf16)sv[j * 4 + 1],
                   (__bf16)sv[j * 4 + 2], (__bf16)sv[j * 4 + 3]};
      *(bf16x4*)&Ps[(w * 16 + mr) * 72 + j * 16 + quad * 4] = pk;
    }
#pragma unroll
    for (int r = 0; r < 4; ++r) {
      float cr = __shfl(corr, quad * 4 + r);
#pragma unroll
      for (int j = 0; j < 4; ++j) o[j][r] *= cr;
    }
    bf16x8 ap0 = *(const bf16x8*)&Ps[(w * 16 + mr) * 72 + quad * 8];
    bf16x8 ap1 = *(const bf16x8*)&Ps[(w * 16 + mr) * 72 + quad * 8 + 32];
#pragma unroll
    for (int j = 0; j < 4; ++j) {
      bf16x8 b0 = *(const bf16x8*)&Vt[(j * 16 + mr) * 72 + quad * 8];
      bf16x8 b1 = *(const bf16x8*)&Vt[(j * 16 + mr) * 72 + quad * 8 + 32];
      o[j] = __builtin_amdgcn_mfma_f32_16x16x32_bf16(ap0, b0, o[j], 0, 0, 0);
      o[j] = __builtin_amdgcn_mfma_f32_16x16x32_bf16(ap1, b1, o[j], 0, 0, 0);
    }
  }
  float invl = 1.f / l_;
#pragma unroll
  for (int r = 0; r < 4; ++r) {
    float ir = __shfl(invl, quad * 4 + r);
    int row = b * kNV + qt * 64 + w * 16 + quad * 4 + r;
#pragma unroll
    for (int j = 0; j < 4; ++j)
      outbf[(size_t)row * kHA + h * kA + j * 16 + mr] = (__bf16)(o[j][r] * ir);
  }
}

// ---- ln2: att = LN(y32 + f3); wave-per-row, no LDS, no barrier -------------
__global__ __launch_bounds__(256) void add_ln2_kernel(
    float* __restrict__ att, const float* __restrict__ y32,
    const __bf16* __restrict__ f3, const float* __restrict__ g,
    const float* __restrict__ be, __bf16* __restrict__ attbf) {
  const int w = threadIdx.x >> 6, lane = threadIdx.x & 63;
  const int row = blockIdx.x * 4 + w;
  const int c0 = lane * 8;
  const size_t base = (size_t)row * kHA + c0;
  float4 a0 = *(const float4*)(y32 + base);
  float4 a1 = *(const float4*)(y32 + base + 4);
  bf16x8 dv = *(const bf16x8*)(f3 + base);
  float x[8] = {a0.x + (float)dv[0], a0.y + (float)dv[1], a0.z + (float)dv[2],
                a0.w + (float)dv[3], a1.x + (float)dv[4], a1.y + (float)dv[5],
                a1.z + (float)dv[6], a1.w + (float)dv[7]};
  float s = 0.f, q = 0.f;
#pragma unroll
  for (int j = 0; j < 8; ++j) { s += x[j]; q += x[j] * x[j]; }
#pragma unroll
  for (int o = 1; o < 64; o <<= 1) {
    s += __shfl_xor(s, o);
    q += __shfl_xor(q, o);
  }
  const float mean = s * (1.f / kHA);
  const float inv = rsqrtf(q * (1.f / kHA) - mean * mean + 1e-5f);
  float4 g0 = *(const float4*)(g + c0);
  float4 g1 = *(const float4*)(g + c0 + 4);
  float4 e0 = *(const float4*)(be + c0);
  float4 e1 = *(const float4*)(be + c0 + 4);
  float y[8];
  y[0] = g0.x * (x[0] - mean) * inv + e0.x;
  y[1] = g0.y * (x[1] - mean) * inv + e0.y;
  y[2] = g0.z * (x[2] - mean) * inv + e0.z;
  y[3] = g0.w * (x[3] - mean) * inv + e0.w;
  y[4] = g1.x * (x[4] - mean) * inv + e1.x;
  y[5] = g1.y * (x[5] - mean) * inv + e1.y;
  y[6] = g1.z * (x[6] - mean) * inv + e1.z;
  y[7] = g1.w * (x[7] - mean) * inv + e1.w;
  *(float4*)(att + base) = (float4){y[0], y[1], y[2], y[3]};
  *(float4*)(att + base + 4) = (float4){y[4], y[5], y[6], y[7]};
  bf16x8 yb = {(__bf16)y[0], (__bf16)y[1], (__bf16)y[2], (__bf16)y[3],
               (__bf16)y[4], (__bf16)y[5], (__bf16)y[6], (__bf16)y[7]};
  *(bf16x8*)(attbf + base) = yb;
}

// ------- fused LN2(l=3) + de-projection + loss (atomic into out) ------------
__global__ __launch_bounds__(256) void de_loss_kernel(
    const float* __restrict__ y32, const __bf16* __restrict__ fbf,
    const float* __restrict__ g2, const float* __restrict__ b2,
    const __bf16* __restrict__ de_wt, const float* __restrict__ de_b,
    const float* __restrict__ pred_u, float* __restrict__ out) {
  __shared__ __bf16 Als[64 * 512];  // 64 KB, row-XOR swizzled
  __shared__ float red[4];
  const int blk = blockIdx.x;
  const int t = threadIdx.x;
  const int w = t >> 6, lane = t & 63, quad = lane >> 4, mr = lane & 15;
  // ---- phase A: LN2 into LDS ----
  {
    const int c0 = lane * 8;
    float4 ga = *(const float4*)(g2 + c0);
    float4 gb = *(const float4*)(g2 + c0 + 4);
    float4 ba = *(const float4*)(b2 + c0);
    float4 bb = *(const float4*)(b2 + c0 + 4);
    for (int rr = 0; rr < 16; ++rr) {
      const int lrow = w * 16 + rr;
      const size_t base = (size_t)(blk * 64 + lrow) * 512 + c0;
      float4 a0 = *(const float4*)(y32 + base);
      float4 a1 = *(const float4*)(y32 + base + 4);
      bf16x8 dv = *(const bf16x8*)(fbf + base);
      float x[8] = {a0.x + (float)dv[0], a0.y + (float)dv[1],
                    a0.z + (float)dv[2], a0.w + (float)dv[3],
                    a1.x + (float)dv[4], a1.y + (float)dv[5],
                    a1.z + (float)dv[6], a1.w + (float)dv[7]};
      float s = 0.f, q = 0.f;
#pragma unroll
      for (int j = 0; j < 8; ++j) { s += x[j]; q += x[j] * x[j]; }
#pragma unroll
      for (int o = 1; o < 64; o <<= 1) {
        s += __shfl_xor(s, o);
        q += __shfl_xor(q, o);
      }
      const float mean = s * (1.f / kHA);
      const float inv = rsqrtf(q * (1.f / kHA) - mean * mean + 1e-5f);
      bf16x8 yv = {(__bf16)(ga.x * (x[0] - mean) * inv + ba.x),
                   (__bf16)(ga.y * (x[1] - mean) * inv + ba.y),
                   (__bf16)(ga.z * (x[2] - mean) * inv + ba.z),
                   (__bf16)(ga.w * (x[3] - mean) * inv + ba.w),
                   (__bf16)(gb.x * (x[4] - mean) * inv + bb.x),
                   (__bf16)(gb.y * (x[5] - mean) * inv + bb.y),
                   (__bf16)(gb.z * (x[6] - mean) * inv + bb.z),
                   (__bf16)(gb.w * (x[7] - mean) * inv + bb.w)};
      *(bf16x8*)&Als[lrow * 512 + ((lane ^ (lrow & 7)) << 3)] = yv;
    }
  }
  __syncthreads();
  // ---- MFMA K-loop (A from LDS) ----
  const int row0 = blk * 64 + w * 16;
  const int lrowA = w * 16 + mr;
  f32x4 acc[8] = {};
#pragma unroll 4
  for (int k0 = 0; k0 < 512; k0 += 32) {
    const int grp = (((k0 >> 3) + quad) ^ (lrowA & 7)) << 3;
    bf16x8 a = *(const bf16x8*)&Als[lrowA * 512 + grp];
#pragma unroll
    for (int j = 0; j < 8; ++j) {
      bf16x8 bb =
          *(const bf16x8*)(de_wt + (size_t)(j * 16 + mr) * 512 + k0 + quad * 8);
      acc[j] = __builtin_amdgcn_mfma_f32_16x16x32_bf16(a, bb, acc[j], 0, 0, 0);
    }
  }
  float dbv[8];
#pragma unroll
  for (int j = 0; j < 8; ++j) dbv[j] = de_b[j * 16 + mr];
  float lpacc = 0.f;
#pragma unroll
  for (int r = 0; r < 4; ++r) {
    int row = row0 + quad * 4 + r;
    int v = row & 255;
    float lg[8], mx = -1e30f;
#pragma unroll
    for (int j = 0; j < 8; ++j) {
      lg[j] = acc[j][r] + dbv[j];
      mx = fmaxf(mx, lg[j]);
    }
    mx = fmaxf(mx, __shfl_xor(mx, 1));
    mx = fmaxf(mx, __shfl_xor(mx, 2));
    mx = fmaxf(mx, __shfl_xor(mx, 4));
    mx = fmaxf(mx, __shfl_xor(mx, 8));
    float se = 0.f;
#pragma unroll
    for (int j = 0; j < 8; ++j) se += __expf(lg[j] - mx);
    se += __shfl_xor(se, 1);
    se += __shfl_xor(se, 2);
    se += __shfl_xor(se, 4);
    se += __shfl_xor(se, 8);
    float lse = mx + __logf(se);
    float u = pred_u[(row >> 8) * 256 + v];
    int tgt = (int)floorf(u * 128.f);
    tgt = max(0, min(127, tgt));
    float cand = (mr == (tgt & 15)) ? lg[tgt >> 4] : 0.f;
    cand += __shfl_xor(cand, 1);
    cand += __shfl_xor(cand, 2);
    cand += __shfl_xor(cand, 4);
    cand += __shfl_xor(cand, 8);
    float lp = (v >= 1) ? (4.8520302639196171f + cand - lse) : 0.f;  // ln(128)
    lpacc += lp;
  }
  lpacc += __shfl_xor(lpacc, 16);
  lpacc += __shfl_xor(lpacc, 32);
  if (lane == 0) red[w] = lpacc;
  __syncthreads();
  if (t == 0)
    atomicAdd(&out[blk >> 2], -(red[0] + red[1] + red[2] + red[3]));
}

extern "C" void kernel_launch(void* const* d_in, const int* in_sizes, int n_in,
                              void* d_out, int out_size, void* d_ws, size_t ws_size,
                              hipStream_t stream) {
  const float* hist   = (const float*)d_in[0];
  const float* hist_u = (const float*)d_in[1];
  const float* pred   = (const float*)d_in[2];
  const float* pred_u = (const float*)d_in[3];
  const float* ds_w   = (const float*)d_in[4];
  const float* ds_b   = (const float*)d_in[5];
  const float* key_w  = (const float*)d_in[6];
  const float* key_b  = (const float*)d_in[7];
  const float* val_w  = (const float*)d_in[8];
  const float* val_b  = (const float*)d_in[9];
  const float* ln1_g  = (const float*)d_in[10];
  const float* ln1_b  = (const float*)d_in[11];
  const float* ln2_g  = (const float*)d_in[12];
  const float* ln2_b  = (const float*)d_in[13];
  const float* ff_w1  = (const float*)d_in[14];
  const float* ff_b1  = (const float*)d_in[15];
  const float* ff_w2  = (const float*)d_in[16];
  const float* ff_b2  = (const float*)d_in[17];
  const float* ff_w3  = (const float*)d_in[18];
  const float* ff_b3  = (const float*)d_in[19];
  const float* de_w   = (const float*)d_in[20];
  const float* de_b   = (const float*)d_in[21];
  float* out = (float*)d_out;

  char* ws = (char*)d_ws;
  size_t off = 0;
  auto alloc = [&](size_t bytes) { char* p = ws + off; off += bytes; return p; };
  __bf16* ki_bf  = (__bf16*)alloc((size_t)kB * kW * kKP * 2);       // 7.1 MB
  __bf16* kv_wt  = (__bf16*)alloc((size_t)4096 * kKP * 2);          // 2.4 MB
  __bf16* ffw_t  = (__bf16*)alloc((size_t)12 * 512 * 512 * 2);      // 6.3 MB
  __bf16* ds_wt  = (__bf16*)alloc((size_t)512 * 256 * 2);
  __bf16* de_wt  = (__bf16*)alloc((size_t)128 * 512 * 2);
  float*  kvb    = (float*)alloc((size_t)4096 * 4);
  __bf16* kvs_k  = (__bf16*)alloc((size_t)kB * kW * 2048 * 2);      // 50.3 MB
  __bf16* vT     = (__bf16*)alloc((size_t)2048 * 12288 * 2);        // 50.3 MB
  float*  att    = (float*)alloc((size_t)kRows * kHA * 4);          // 8.4 MB
  float*  y32    = (float*)alloc((size_t)kRows * kHA * 4);          // 8.4 MB
  __bf16* att_bf = (__bf16*)alloc((size_t)kRows * kHA * 2);
  __bf16* tmp_bf = (__bf16*)alloc((size_t)kRows * kHA * 2);
  __bf16* ff1_bf = (__bf16*)alloc((size_t)kRows * kM * 2);
  __bf16* ff2_bf = (__bf16*)alloc((size_t)kRows * kM * 2);

  prep_kernel<<<kPrepBlocks, 256, 0, stream>>>(
      hist, hist_u, pred, pred_u, key_w, val_w, ff_w1, ff_w2, ff_w3, ds_w, de_w,
      key_b, val_b, ki_bf, kv_wt, ffw_t, ds_wt, de_wt, kvb, out);

  // ds + keys + vT in one launch
  gemm3_kernel<<<3328, 256, 0, stream>>>(ki_bf, ds_wt, ds_b, att, att_bf, kv_wt,
                                         kvb, kvs_k, vT);

  for (int l = 0; l < kL; ++l) {
    attn_mfma_kernel<<<512, 256, 0, stream>>>(att_bf, kvs_k, vT, tmp_bf, l);
    // LN1 fused into ff1 (row-complete tiles; y kept in y32)
    ff1_fused_kernel<<<256, 256, 0, stream>>>(
        att, tmp_bf, ln1_g + l * kHA, ln1_b + l * kHA,
        ffw_t + (size_t)(l * 3) * 262144, ff_b1 + l * kM, y32, ff1_bf);
    gemm_ff_kernel<true><<<dim3(kM / 64, kRows / 128), 256, 0, stream>>>(
        ff1_bf, ffw_t + (size_t)(l * 3 + 1) * 262144, ff_b2 + l * kM, ff2_bf);
    gemm_ff_kernel<false><<<dim3(kHA / 64, kRows / 128), 256, 0, stream>>>(
        ff2_bf, ffw_t + (size_t)(l * 3 + 2) * 262144, ff_b3 + l * kHA, tmp_bf);
    if (l < kL - 1)
      add_ln2_kernel<<<kRows / 4, 256, 0, stream>>>(
          att, y32, tmp_bf, ln2_g + l * kHA, ln2_b + l * kHA, att_bf);
  }
  // final LN2 fused into de_loss (y32 = layer-3 LN1 out; tmp_bf = ff3)
  de_loss_kernel<<<64, 256, 0, stream>>>(y32, tmp_bf, ln2_g + 3 * kHA,
                                         ln2_b + 3 * kHA, de_wt, de_b, pred_u,
                                         out);
}

// Round 12
// 412.172 us; speedup vs baseline: 2.4625x; 1.0807x over previous
//
#include <hip/hip_runtime.h>

// Problem constants (AttentionalCopula)
constexpr int kB = 16, kD = 256, kNH = 512, kNV = 256, kW = 768;
constexpr int kL = 4, kH = 8, kA = 64, kHA = 512, kM = 512, kR = 128;
constexpr int kKP = 288;  // K=257 zero-padded to multiple of 32
constexpr int kRows = kB * kNV;  // 4096

typedef __bf16 bf16x8 __attribute__((ext_vector_type(8)));
typedef __bf16 bf16x4 __attribute__((ext_vector_type(4)));
typedef __bf16 bf16x2 __attribute__((ext_vector_type(2)));
typedef float f32x4 __attribute__((ext_vector_type(4)));

__device__ inline void load_lds16(const __bf16* g, __bf16* l) {
  __builtin_amdgcn_global_load_lds(
      (const __attribute__((address_space(1))) void*)g,
      (__attribute__((address_space(3))) void*)l, 16, 0, 0);
}

// ---------------- merged prep kernel (1 launch, block-range sections) --------
// A: ki fill, 2 elems/thread            [0, 6912)
// B: kv weights transpose (LDS-tiled)   [6912, 7488)
// C: ff weights transpose (LDS-tiled)   [7488, 10560)
// D: ds_w transpose                     [10560, 10688)
// E: de_w transpose                     [10688, 10752)
// F: kvb gather + out zero              [10752, 10769)
constexpr int kPrepBlocks = 10769;

__global__ void prep_kernel(const float* __restrict__ hist,
                            const float* __restrict__ hist_u,
                            const float* __restrict__ pred,
                            const float* __restrict__ pred_u,
                            const float* __restrict__ kw,
                            const float* __restrict__ vw,
                            const float* __restrict__ w1,
                            const float* __restrict__ w2,
                            const float* __restrict__ w3,
                            const float* __restrict__ ds_w,
                            const float* __restrict__ de_w,
                            const float* __restrict__ key_b,
                            const float* __restrict__ val_b,
                            __bf16* __restrict__ ki,
                            __bf16* __restrict__ kvwt,
                            __bf16* __restrict__ ffwt,
                            __bf16* __restrict__ ds_wt,
                            __bf16* __restrict__ de_wt,
                            float* __restrict__ kvb,
                            float* __restrict__ outz) {
  __shared__ float ld[2080];  // 32x65 (B) / 32x33 (C,D,E)
  const int bid = blockIdx.x;
  const int t = threadIdx.x;
  if (bid < 6912) {
    // ---- A: ki fill (2 elems/thread, bf16x2 store) ----
    int i = bid * 512 + t * 2;
    __bf16 v2[2];
#pragma unroll
    for (int e = 0; e < 2; ++e) {
      int ii = i + e;
      int d = ii % kKP;
      int bw = ii / kKP;
      int w = bw % kW;
      int b = bw / kW;
      float v = 0.f;
      if (d < 257) {
        if (w < kNH)
          v = (d < kD) ? hist[((size_t)b * kNH + w) * kD + d]
                       : hist_u[b * kNH + w];
        else {
          int p = w - kNH;
          v = (d < kD) ? pred[((size_t)b * kNV + p) * kD + d]
                       : pred_u[b * kNV + p];
        }
      }
      v2[e] = (__bf16)v;
    }
    *(bf16x2*)&ki[i] = bf16x2{v2[0], v2[1]};
  } else if (bid < 7488) {
    // ---- B: kv weight transpose ----
    int bb = bid - 6912;
    bool isv = bb >= 288;
    int rem = isv ? bb - 288 : bb;
    int pair = rem / 9;
    int dt = rem - pair * 9;
    int d0 = dt * 32;
    const float* src = (isv ? vw : kw) + (size_t)pair * 257 * 64;
    int a = t & 63, dg = t >> 6;
#pragma unroll
    for (int ii = 0; ii < 8; ++ii) {
      int d = d0 + dg * 8 + ii;
      ld[(dg * 8 + ii) * 65 + a] = (d < 257) ? src[(size_t)d * 64 + a] : 0.f;
    }
    __syncthreads();
    int r = t >> 2, seg = t & 3;
    bf16x8 v;
#pragma unroll
    for (int j = 0; j < 8; ++j) v[j] = (__bf16)ld[(seg * 8 + j) * 65 + r];
    *(bf16x8*)&kvwt[((size_t)(isv ? 2048 : 0) + pair * 64 + r) * 288 + d0 +
                    seg * 8] = v;
  } else if (bid < 10560) {
    // ---- C: ff weight transpose ----
    int cc = bid - 7488;
    int mat = cc >> 8;
    int tile = cc & 255;
    int n0 = (tile & 15) * 32, k0 = (tile >> 4) * 32;
    int l = mat / 3, which = mat - l * 3;
    const float* src = (which == 0 ? w1 : which == 1 ? w2 : w3) +
                       (size_t)l * 262144;
    int col = t & 31, kr = t >> 5;
#pragma unroll
    for (int p = 0; p < 4; ++p)
      ld[(kr + p * 8) * 33 + col] = src[(size_t)(k0 + kr + p * 8) * 512 + n0 + col];
    __syncthreads();
    int nr = t >> 3, seg = t & 7;
    bf16x4 v;
#pragma unroll
    for (int j = 0; j < 4; ++j) v[j] = (__bf16)ld[(seg * 4 + j) * 33 + nr];
    *(bf16x4*)&ffwt[(size_t)mat * 262144 + (n0 + nr) * 512 + k0 + seg * 4] = v;
  } else if (bid < 10688) {
    // ---- D: ds_w transpose ----
    int cc = bid - 10560;
    int n0 = (cc & 15) * 32, k0 = (cc >> 4) * 32;
    int col = t & 31, kr = t >> 5;
#pragma unroll
    for (int p = 0; p < 4; ++p)
      ld[(kr + p * 8) * 33 + col] = ds_w[(size_t)(k0 + kr + p * 8) * 512 + n0 + col];
    __syncthreads();
    int nr = t >> 3, seg = t & 7;
    bf16x4 v;
#pragma unroll
    for (int j = 0; j < 4; ++j) v[j] = (__bf16)ld[(seg * 4 + j) * 33 + nr];
    *(bf16x4*)&ds_wt[(n0 + nr) * 256 + k0 + seg * 4] = v;
  } else if (bid < 10752) {
    // ---- E: de_w transpose ----
    int cc = bid - 10688;
    int n0 = (cc & 3) * 32, k0 = (cc >> 2) * 32;
    int col = t & 31, kr = t >> 5;
#pragma unroll
    for (int p = 0; p < 4; ++p)
      ld[(kr + p * 8) * 33 + col] = de_w[(size_t)(k0 + kr + p * 8) * 128 + n0 + col];
    __syncthreads();
    int nr = t >> 3, seg = t & 7;
    bf16x4 v;
#pragma unroll
    for (int j = 0; j < 4; ++j) v[j] = (__bf16)ld[(seg * 4 + j) * 33 + nr];
    *(bf16x4*)&de_wt[(n0 + nr) * 512 + k0 + seg * 4] = v;
  } else {
    // ---- F: kvb + out zero ----
    int j = (bid - 10752) * 256 + t;
    if (j < 4096) {
      bool isv = j >= 2048;
      int cc = isv ? j - 2048 : j;
      int l = cc >> 9, rest = cc & 511;
      kvb[j] = isv ? val_b[l * 512 + rest] : key_b[l * 512 + rest];
    } else if (j < 4112) {
      outz[j - 4096] = 0.f;
    }
  }
}

// ---- generic bf16 MFMA GEMM core (DEPTH-buffer counted-vmcnt pipeline) ------
template <int BN, int OMODE, bool RELU, bool KIMAP, bool BIASROW, int DEPTH>
__device__ __forceinline__ void gemm_core(
    int bxv, int byv, const __bf16* __restrict__ A,
    const __bf16* __restrict__ Bt, const float* __restrict__ bias,
    void* __restrict__ Cout, __bf16* __restrict__ Cout2, int K, int lda,
    int ldc, __bf16* Sm) {
  constexpr int JN = BN / 32;
  constexpr int BROWS = BN / 4;
  constexpr int SSTEP = (128 + BN) * 32;
  constexpr int LPS = (BN == 128) ? 4 : 3;
  constexpr int AH = DEPTH - 1;
  const int t = threadIdx.x;
  const int wid = t >> 6;
  const int lane = t & 63;
  const int bm = byv * 128;
  const int bn = bxv * BN;
  const int wm = (wid >> 1) * 64;
  const int wn = (wid & 1) * (BN / 2);
  const int sr = lane >> 2, sc = lane & 3;
  const int skey = (sr >> 1) & 3;
  const int abase = KIMAP ? ((bm >> 8) * 768 + 512 + (bm & 255)) : bm;
  const __bf16* Ag = A + (size_t)(abase + wid * 32 + sr) * lda + (sc ^ skey) * 8;
  const __bf16* Bg = Bt + (size_t)(bn + wid * BROWS + sr) * K + (sc ^ skey) * 8;

  auto stage = [&](int k0, __bf16* buf) {
    __bf16* As = buf;
    __bf16* Bs = buf + 4096;
    load_lds16(Ag + k0, As + (wid * 32) * 32);
    load_lds16(Ag + (size_t)16 * lda + k0, As + (wid * 32 + 16) * 32);
    load_lds16(Bg + k0, Bs + (wid * BROWS) * 32);
    if (BN == 128)
      load_lds16(Bg + (size_t)16 * K + k0, Bs + (wid * BROWS + 16) * 32);
  };

  f32x4 acc[4][JN] = {};
  const int q = lane >> 4, mr = lane & 15;
  const int rkey = (mr >> 1) & 3;
  const int nst = K >> 5;
  __bf16* b0 = Sm;
  __bf16* b1 = Sm + SSTEP;
  __bf16* b2 = Sm + 2 * SSTEP;
  __bf16* b3 = (DEPTH == 4) ? Sm + 3 * SSTEP : nullptr;
  stage(0, b0);
  stage(32, b1);
  if constexpr (DEPTH == 4) stage(64, b2);
  asm volatile("s_waitcnt vmcnt(%0)" ::"n"((AH - 1) * LPS) : "memory");
  __builtin_amdgcn_s_barrier();
  for (int k = 0; k < nst; ++k) {
    if (k + AH < nst) {
      if constexpr (DEPTH == 4) stage((k + AH) << 5, b3);
      else stage((k + AH) << 5, b2);
    }
    bf16x8 af[4], bfr[JN];
#pragma unroll
    for (int i = 0; i < 4; ++i)
      af[i] = *(const bf16x8*)(b0 + (wm + i * 16 + mr) * 32 + (q ^ rkey) * 8);
#pragma unroll
    for (int j = 0; j < JN; ++j)
      bfr[j] =
          *(const bf16x8*)(b0 + 4096 + (wn + j * 16 + mr) * 32 + (q ^ rkey) * 8);
#pragma unroll
    for (int i = 0; i < 4; ++i)
#pragma unroll
      for (int j = 0; j < JN; ++j)
        acc[i][j] = __builtin_amdgcn_mfma_f32_16x16x32_bf16(af[i], bfr[j],
                                                            acc[i][j], 0, 0, 0);
    if (k + AH + 1 <= nst)
      asm volatile("s_waitcnt vmcnt(%0)" ::"n"((AH - 1) * LPS) : "memory");
    else if (DEPTH == 4 && k + AH == nst + 1)
      asm volatile("s_waitcnt vmcnt(%0)" ::"n"(LPS) : "memory");
    else
      asm volatile("s_waitcnt vmcnt(0)" ::: "memory");
    __builtin_amdgcn_s_barrier();
    if constexpr (DEPTH == 4) {
      __bf16* tp = b0; b0 = b1; b1 = b2; b2 = b3; b3 = tp;
    } else {
      __bf16* tp = b0; b0 = b1; b1 = b2; b2 = tp;
    }
  }
  // ---- epilogue: stage C in LDS, coalesced write-out ----
  if (OMODE == 1) {
    constexpr int PS = BN + 8;
    __bf16* Cs = Sm;
#pragma unroll
    for (int j = 0; j < JN; ++j) {
      float bscol = BIASROW ? 0.f : bias[bn + wn + j * 16 + mr];
#pragma unroll
      for (int i = 0; i < 4; ++i) {
#pragma unroll
        for (int r = 0; r < 4; ++r) {
          float v = acc[i][j][r] +
                    (BIASROW ? bias[bm + wm + i * 16 + q * 4 + r] : bscol);
          if (RELU) v = fmaxf(v, 0.f);
          Cs[(wm + i * 16 + q * 4 + r) * PS + wn + j * 16 + mr] = (__bf16)v;
        }
      }
    }
    __syncthreads();
    constexpr int lpr = BN / 8;
    constexpr int rpi = 512 / BN;
    const int rl = lane / lpr, cl = (lane % lpr) * 8;
#pragma unroll
    for (int it = 0; it < BN / 16; ++it) {
      int row = wid * 32 + it * rpi + rl;
      bf16x8 v = *(const bf16x8*)&Cs[row * PS + cl];
      *(bf16x8*)((__bf16*)Cout + (size_t)(bm + row) * ldc + bn + cl) = v;
    }
  } else {
    constexpr int PSF = BN + 4;
    float* Csf = (float*)Sm;
#pragma unroll
    for (int j = 0; j < JN; ++j) {
      float bscol = bias[bn + wn + j * 16 + mr];
#pragma unroll
      for (int i = 0; i < 4; ++i) {
#pragma unroll
        for (int r = 0; r < 4; ++r) {
          float v = acc[i][j][r] + bscol;
          if (RELU) v = fmaxf(v, 0.f);
          Csf[(wm + i * 16 + q * 4 + r) * PSF + wn + j * 16 + mr] = v;
        }
      }
    }
    __syncthreads();
    const int rl = lane >> 4, cl = (lane & 15) * 4;
#pragma unroll
    for (int it = 0; it < 8; ++it) {
      int row = wid * 32 + it * 4 + rl;
      f32x4 v = *(const f32x4*)&Csf[row * PSF + cl];
      size_t gidx = (size_t)(bm + row) * ldc + bn + cl;
      *(f32x4*)((float*)Cout + gidx) = v;
      bf16x4 vb = {(__bf16)v[0], (__bf16)v[1], (__bf16)v[2], (__bf16)v[3]};
      *(bf16x4*)(Cout2 + gidx) = vb;
    }
  }
}

// ---------------- fused ds + keys + vT GEMM (one launch, 3328 blocks) ----------------
__global__ __launch_bounds__(256) void gemm3_kernel(
    const __bf16* __restrict__ ki, const __bf16* __restrict__ ds_wt,
    const float* __restrict__ ds_b, float* __restrict__ att,
    __bf16* __restrict__ att_bf, const __bf16* __restrict__ kv_wt,
    const float* __restrict__ kvb, __bf16* __restrict__ kvs_k,
    __bf16* __restrict__ vT) {
  __shared__ __bf16 smem[32768];  // D4 staging for BN=128: 4*8192 = 32768
  int bid = blockIdx.x;  // identity mapping (both swizzles measured worse)
  if (bid < 256) {
    gemm_core<64, 2, false, true, false, 3>(bid & 7, bid >> 3, ki, ds_wt, ds_b,
                                            att, att_bf, 256, kKP, 512, smem);
  } else if (bid < 1792) {
    int b2 = bid - 256;
    gemm_core<128, 1, false, false, false, 4>(b2 & 15, b2 >> 4, ki, kv_wt, kvb,
                                              kvs_k, nullptr, kKP, kKP, 2048,
                                              smem);
  } else {
    int b3 = bid - 1792;
    gemm_core<128, 1, false, false, true, 4>(b3 % 96, b3 / 96,
                                             kv_wt + (size_t)2048 * kKP, ki,
                                             kvb + 2048, vT, nullptr, kKP, kKP,
                                             12288, smem);
  }
}

// ---------------- ff GEMMs (gemm_core wrappers, 4-deep pipeline) ------------
template <bool RELU>
__global__ __launch_bounds__(256) void gemm_ff_kernel(
    const __bf16* __restrict__ A, const __bf16* __restrict__ Bt,
    const float* __restrict__ bias, __bf16* __restrict__ Cout) {
  __shared__ __bf16 smem[24576];
  gemm_core<64, 1, RELU, false, false, 4>(blockIdx.x, blockIdx.y, A, Bt, bias,
                                          Cout, nullptr, 512, 512, 512, smem);
}

// ------ MFMA flash attention (S^T, double-buffered K/V, 1 barrier/tile) -----
// Ps is wave-private (same-wave rows written+read) -> no barrier needed for it.
__global__ __launch_bounds__(256) void attn_mfma_kernel(
    const __bf16* __restrict__ attbf, const __bf16* __restrict__ kvs_k,
    const __bf16* __restrict__ vT, __bf16* __restrict__ outbf, int l) {
  const int id = blockIdx.x;
  const int kk = id >> 3;
  const int b = ((kk >> 5) << 3) | (id & 7);
  const int qt = kk & 3;
  const int h = (kk >> 2) & 7;
  __shared__ __bf16 Ks[2][64 * 72];
  __shared__ __bf16 Vt[2][64 * 72];
  __shared__ __bf16 Ps[64 * 72];
  const int t = threadIdx.x;
  const int w = t >> 6, lane = t & 63;
  const int quad = lane >> 4, mr = lane & 15;
  bf16x8 aq[2];
  {
    const __bf16* qp = attbf + ((size_t)(b * kNV + qt * 64 + w * 16 + mr) * kHA +
                                h * kA + quad * 8);
    aq[0] = *(const bf16x8*)qp;
    aq[1] = *(const bf16x8*)(qp + 32);
  }
  f32x4 o[4] = {};
  float m_ = -1e30f, l_ = 0.f;
  const int cmax = kNH + qt * 64;
  const int nt = (cmax >> 6) + 1;
  const int pr = t >> 2, pc = t & 3;
  const __bf16* kbase = kvs_k + ((size_t)(b * kW + pr) * 2048 + l * 512 + h * kA);
  const __bf16* vbase = vT + (size_t)(l * 512 + h * kA + pr) * 12288 + b * kW;
  bf16x8 kc0, kc1, vc0, vc1;
  auto loadt = [&](int tt) {
    const __bf16* kp = kbase + (size_t)(tt << 6) * 2048;
    const __bf16* vp = vbase + (tt << 6);
    kc0 = *(const bf16x8*)(kp + pc * 8);
    kc1 = *(const bf16x8*)(kp + pc * 8 + 32);
    vc0 = *(const bf16x8*)(vp + pc * 16);
    vc1 = *(const bf16x8*)(vp + pc * 16 + 8);
  };
  auto writet = [&](int buf) {
    *(bf16x8*)&Ks[buf][pr * 72 + pc * 8] = kc0;
    *(bf16x8*)&Ks[buf][pr * 72 + pc * 8 + 32] = kc1;
    *(bf16x8*)&Vt[buf][pr * 72 + pc * 16] = vc0;
    *(bf16x8*)&Vt[buf][pr * 72 + pc * 16 + 8] = vc1;
  };
  loadt(0);
  writet(0);
  if (nt > 1) loadt(1);
  __syncthreads();
  for (int tt = 0; tt < nt; ++tt) {
    const int cur = tt & 1;
    // ---- S^T = K·Q^T ----
    f32x4 s[4];
#pragma unroll
    for (int j = 0; j < 4; ++j) {
      bf16x8 ak0 = *(const bf16x8*)&Ks[cur][(j * 16 + mr) * 72 + quad * 8];
      bf16x8 ak1 = *(const bf16x8*)&Ks[cur][(j * 16 + mr) * 72 + quad * 8 + 32];
      f32x4 z = {};
      z = __builtin_amdgcn_mfma_f32_16x16x32_bf16(ak0, aq[0], z, 0, 0, 0);
      z = __builtin_amdgcn_mfma_f32_16x16x32_bf16(ak1, aq[1], z, 0, 0, 0);
      s[j] = z;
    }
    const int lim = cmax - (tt << 6);
    float sv[16], mx = -1e30f;
#pragma unroll
    for (int j = 0; j < 4; ++j)
#pragma unroll
      for (int r = 0; r < 4; ++r) {
        int p = j * 16 + quad * 4 + r;
        float x = (p < lim + mr) ? s[j][r] * 0.125f : -1e30f;
        sv[j * 4 + r] = x;
        mx = fmaxf(mx, x);
      }
    mx = fmaxf(mx, __shfl_xor(mx, 16));
    mx = fmaxf(mx, __shfl_xor(mx, 32));
    float mnew = fmaxf(m_, mx);
    float corr = __expf(m_ - mnew);
    float rs = 0.f;
#pragma unroll
    for (int i = 0; i < 16; ++i) {
      sv[i] = __expf(sv[i] - mnew);
      rs += sv[i];
    }
    rs += __shfl_xor(rs, 16);
    rs += __shfl_xor(rs, 32);
    l_ = l_ * corr + rs;
    m_ = mnew;
#pragma unroll
    for (int j = 0; j < 4; ++j) {
      bf16x4 pk = {(__bf16)sv[j * 4 + 0], (__bf16)sv[j * 4 + 1],
                   (__bf16)sv[j * 4 + 2], (__bf16)sv[j * 4 + 3]};
      *(bf16x4*)&Ps[(w * 16 + mr) * 72 + j * 16 + quad * 4] = pk;
    }
#pragma unroll
    for (int r = 0; r < 4; ++r) {
      float cr = __shfl(corr, quad * 4 + r);
#pragma unroll
      for (int j = 0; j < 4; ++j) o[j][r] *= cr;
    }
    bf16x8 ap0 = *(const bf16x8*)&Ps[(w * 16 + mr) * 72 + quad * 8];
    bf16x8 ap1 = *(const bf16x8*)&Ps[(w * 16 + mr) * 72 + quad * 8 + 32];
#pragma unroll
    for (int j = 0; j < 4; ++j) {
      bf16x8 b0 = *(const bf16x8*)&Vt[cur][(j * 16 + mr) * 72 + quad * 8];
      bf16x8 b1 = *(const bf16x8*)&Vt[cur][(j * 16 + mr) * 72 + quad * 8 + 32];
      o[j] = __builtin_amdgcn_mfma_f32_16x16x32_bf16(ap0, b0, o[j], 0, 0, 0);
      o[j] = __builtin_amdgcn_mfma_f32_16x16x32_bf16(ap1, b1, o[j], 0, 0, 0);
    }
    if (tt + 1 < nt) {
      writet(cur ^ 1);
      if (tt + 2 < nt) loadt(tt + 2);
      __syncthreads();
    }
  }
  float invl = 1.f / l_;
#pragma unroll
  for (int r = 0; r < 4; ++r) {
    float ir = __shfl(invl, quad * 4 + r);
    int row = b * kNV + qt * 64 + w * 16 + quad * 4 + r;
#pragma unroll
    for (int j = 0; j < 4; ++j)
      outbf[(size_t)row * kHA + h * kA + j * 16 + mr] = (__bf16)(o[j][r] * ir);
  }
}

// --------- att = LN(att + add_bf); wave-per-row, no LDS, no barrier ---------
__global__ __launch_bounds__(256) void add_ln_kernel(
    float* __restrict__ att, const __bf16* __restrict__ addbf,
    const float* __restrict__ g, const float* __restrict__ be,
    __bf16* __restrict__ attbf) {
  const int w = threadIdx.x >> 6, lane = threadIdx.x & 63;
  const int row = blockIdx.x * 4 + w;
  const int c0 = lane * 8;
  const size_t base = (size_t)row * kHA + c0;
  float4 a0 = *(const float4*)(att + base);
  float4 a1 = *(const float4*)(att + base + 4);
  bf16x8 dv = *(const bf16x8*)(addbf + base);
  float x[8] = {a0.x + (float)dv[0], a0.y + (float)dv[1], a0.z + (float)dv[2],
                a0.w + (float)dv[3], a1.x + (float)dv[4], a1.y + (float)dv[5],
                a1.z + (float)dv[6], a1.w + (float)dv[7]};
  float s = 0.f, q = 0.f;
#pragma unroll
  for (int j = 0; j < 8; ++j) { s += x[j]; q += x[j] * x[j]; }
#pragma unroll
  for (int o = 1; o < 64; o <<= 1) {
    s += __shfl_xor(s, o);
    q += __shfl_xor(q, o);
  }
  const float mean = s * (1.f / kHA);
  const float inv = rsqrtf(q * (1.f / kHA) - mean * mean + 1e-5f);
  float4 g0 = *(const float4*)(g + c0);
  float4 g1 = *(const float4*)(g + c0 + 4);
  float4 e0 = *(const float4*)(be + c0);
  float4 e1 = *(const float4*)(be + c0 + 4);
  float y[8];
  y[0] = g0.x * (x[0] - mean) * inv + e0.x;
  y[1] = g0.y * (x[1] - mean) * inv + e0.y;
  y[2] = g0.z * (x[2] - mean) * inv + e0.z;
  y[3] = g0.w * (x[3] - mean) * inv + e0.w;
  y[4] = g1.x * (x[4] - mean) * inv + e1.x;
  y[5] = g1.y * (x[5] - mean) * inv + e1.y;
  y[6] = g1.z * (x[6] - mean) * inv + e1.z;
  y[7] = g1.w * (x[7] - mean) * inv + e1.w;
  *(float4*)(att + base) = (float4){y[0], y[1], y[2], y[3]};
  *(float4*)(att + base + 4) = (float4){y[4], y[5], y[6], y[7]};
  bf16x8 yb = {(__bf16)y[0], (__bf16)y[1], (__bf16)y[2], (__bf16)y[3],
               (__bf16)y[4], (__bf16)y[5], (__bf16)y[6], (__bf16)y[7]};
  *(bf16x8*)(attbf + base) = yb;
}

// ------- fused LN2(l=3) + de-projection + loss (atomic into out) ------------
__global__ __launch_bounds__(256) void de_loss_kernel(
    const float* __restrict__ att, const __bf16* __restrict__ fbf,
    const float* __restrict__ g2, const float* __restrict__ b2,
    const __bf16* __restrict__ de_wt, const float* __restrict__ de_b,
    const float* __restrict__ pred_u, float* __restrict__ out) {
  __shared__ __bf16 Als[64 * 512];  // 64 KB, row-XOR swizzled
  __shared__ float red[4];
  const int blk = blockIdx.x;
  const int t = threadIdx.x;
  const int w = t >> 6, lane = t & 63, quad = lane >> 4, mr = lane & 15;
  // ---- phase A: LN2 into LDS ----
  {
    const int c0 = lane * 8;
    float4 ga = *(const float4*)(g2 + c0);
    float4 gb = *(const float4*)(g2 + c0 + 4);
    float4 ba = *(const float4*)(b2 + c0);
    float4 bb = *(const float4*)(b2 + c0 + 4);
    for (int rr = 0; rr < 16; ++rr) {
      const int lrow = w * 16 + rr;
      const size_t base = (size_t)(blk * 64 + lrow) * 512 + c0;
      float4 a0 = *(const float4*)(att + base);
      float4 a1 = *(const float4*)(att + base + 4);
      bf16x8 dv = *(const bf16x8*)(fbf + base);
      float x[8] = {a0.x + (float)dv[0], a0.y + (float)dv[1],
                    a0.z + (float)dv[2], a0.w + (float)dv[3],
                    a1.x + (float)dv[4], a1.y + (float)dv[5],
                    a1.z + (float)dv[6], a1.w + (float)dv[7]};
      float s = 0.f, q = 0.f;
#pragma unroll
      for (int j = 0; j < 8; ++j) { s += x[j]; q += x[j] * x[j]; }
#pragma unroll
      for (int o = 1; o < 64; o <<= 1) {
        s += __shfl_xor(s, o);
        q += __shfl_xor(q, o);
      }
      const float mean = s * (1.f / kHA);
      const float inv = rsqrtf(q * (1.f / kHA) - mean * mean + 1e-5f);
      bf16x8 yv = {(__bf16)(ga.x * (x[0] - mean) * inv + ba.x),
                   (__bf16)(ga.y * (x[1] - mean) * inv + ba.y),
                   (__bf16)(ga.z * (x[2] - mean) * inv + ba.z),
                   (__bf16)(ga.w * (x[3] - mean) * inv + ba.w),
                   (__bf16)(gb.x * (x[4] - mean) * inv + bb.x),
                   (__bf16)(gb.y * (x[5] - mean) * inv + bb.y),
                   (__bf16)(gb.z * (x[6] - mean) * inv + bb.z),
                   (__bf16)(gb.w * (x[7] - mean) * inv + bb.w)};
      *(bf16x8*)&Als[lrow * 512 + ((lane ^ (lrow & 7)) << 3)] = yv;
    }
  }
  __syncthreads();
  // ---- MFMA K-loop (A from LDS) ----
  const int row0 = blk * 64 + w * 16;
  const int lrowA = w * 16 + mr;
  f32x4 acc[8] = {};
#pragma unroll 4
  for (int k0 = 0; k0 < 512; k0 += 32) {
    const int grp = (((k0 >> 3) + quad) ^ (lrowA & 7)) << 3;
    bf16x8 a = *(const bf16x8*)&Als[lrowA * 512 + grp];
#pragma unroll
    for (int j = 0; j < 8; ++j) {
      bf16x8 bb =
          *(const bf16x8*)(de_wt + (size_t)(j * 16 + mr) * 512 + k0 + quad * 8);
      acc[j] = __builtin_amdgcn_mfma_f32_16x16x32_bf16(a, bb, acc[j], 0, 0, 0);
    }
  }
  float dbv[8];
#pragma unroll
  for (int j = 0; j < 8; ++j) dbv[j] = de_b[j * 16 + mr];
  float lpacc = 0.f;
#pragma unroll
  for (int r = 0; r < 4; ++r) {
    int row = row0 + quad * 4 + r;
    int v = row & 255;
    float lg[8], mx = -1e30f;
#pragma unroll
    for (int j = 0; j < 8; ++j) {
      lg[j] = acc[j][r] + dbv[j];
      mx = fmaxf(mx, lg[j]);
    }
    mx = fmaxf(mx, __shfl_xor(mx, 1));
    mx = fmaxf(mx, __shfl_xor(mx, 2));
    mx = fmaxf(mx, __shfl_xor(mx, 4));
    mx = fmaxf(mx, __shfl_xor(mx, 8));
    float se = 0.f;
#pragma unroll
    for (int j = 0; j < 8; ++j) se += __expf(lg[j] - mx);
    se += __shfl_xor(se, 1);
    se += __shfl_xor(se, 2);
    se += __shfl_xor(se, 4);
    se += __shfl_xor(se, 8);
    float lse = mx + __logf(se);
    float u = pred_u[(row >> 8) * 256 + v];
    int tgt = (int)floorf(u * 128.f);
    tgt = max(0, min(127, tgt));
    float cand = (mr == (tgt & 15)) ? lg[tgt >> 4] : 0.f;
    cand += __shfl_xor(cand, 1);
    cand += __shfl_xor(cand, 2);
    cand += __shfl_xor(cand, 4);
    cand += __shfl_xor(cand, 8);
    float lp = (v >= 1) ? (4.8520302639196171f + cand - lse) : 0.f;  // ln(128)
    lpacc += lp;
  }
  lpacc += __shfl_xor(lpacc, 16);
  lpacc += __shfl_xor(lpacc, 32);
  if (lane == 0) red[w] = lpacc;
  __syncthreads();
  if (t == 0)
    atomicAdd(&out[blk >> 2], -(red[0] + red[1] + red[2] + red[3]));
}

extern "C" void kernel_launch(void* const* d_in, const int* in_sizes, int n_in,
                              void* d_out, int out_size, void* d_ws, size_t ws_size,
                              hipStream_t stream) {
  const float* hist   = (const float*)d_in[0];
  const float* hist_u = (const float*)d_in[1];
  const float* pred   = (const float*)d_in[2];
  const float* pred_u = (const float*)d_in[3];
  const float* ds_w   = (const float*)d_in[4];
  const float* ds_b   = (const float*)d_in[5];
  const float* key_w  = (const float*)d_in[6];
  const float* key_b  = (const float*)d_in[7];
  const float* val_w  = (const float*)d_in[8];
  const float* val_b  = (const float*)d_in[9];
  const float* ln1_g  = (const float*)d_in[10];
  const float* ln1_b  = (const float*)d_in[11];
  const float* ln2_g  = (const float*)d_in[12];
  const float* ln2_b  = (const float*)d_in[13];
  const float* ff_w1  = (const float*)d_in[14];
  const float* ff_b1  = (const float*)d_in[15];
  const float* ff_w2  = (const float*)d_in[16];
  const float* ff_b2  = (const float*)d_in[17];
  const float* ff_w3  = (const float*)d_in[18];
  const float* ff_b3  = (const float*)d_in[19];
  const float* de_w   = (const float*)d_in[20];
  const float* de_b   = (const float*)d_in[21];
  float* out = (float*)d_out;

  char* ws = (char*)d_ws;
  size_t off = 0;
  auto alloc = [&](size_t bytes) { char* p = ws + off; off += bytes; return p; };
  __bf16* ki_bf  = (__bf16*)alloc((size_t)kB * kW * kKP * 2);       // 7.1 MB
  __bf16* kv_wt  = (__bf16*)alloc((size_t)4096 * kKP * 2);          // 2.4 MB
  __bf16* ffw_t  = (__bf16*)alloc((size_t)12 * 512 * 512 * 2);      // 6.3 MB
  __bf16* ds_wt  = (__bf16*)alloc((size_t)512 * 256 * 2);
  __bf16* de_wt  = (__bf16*)alloc((size_t)128 * 512 * 2);
  float*  kvb    = (float*)alloc((size_t)4096 * 4);
  __bf16* kvs_k  = (__bf16*)alloc((size_t)kB * kW * 2048 * 2);      // 50.3 MB
  __bf16* vT     = (__bf16*)alloc((size_t)2048 * 12288 * 2);        // 50.3 MB
  float*  att    = (float*)alloc((size_t)kRows * kHA * 4);          // 8.4 MB
  __bf16* att_bf = (__bf16*)alloc((size_t)kRows * kHA * 2);
  __bf16* tmp_bf = (__bf16*)alloc((size_t)kRows * kHA * 2);
  __bf16* ff1_bf = (__bf16*)alloc((size_t)kRows * kM * 2);
  __bf16* ff2_bf = (__bf16*)alloc((size_t)kRows * kM * 2);

  prep_kernel<<<kPrepBlocks, 256, 0, stream>>>(
      hist, hist_u, pred, pred_u, key_w, val_w, ff_w1, ff_w2, ff_w3, ds_w, de_w,
      key_b, val_b, ki_bf, kv_wt, ffw_t, ds_wt, de_wt, kvb, out);

  // ds + keys + vT in one launch
  gemm3_kernel<<<3328, 256, 0, stream>>>(ki_bf, ds_wt, ds_b, att, att_bf, kv_wt,
                                         kvb, kvs_k, vT);

  for (int l = 0; l < kL; ++l) {
    attn_mfma_kernel<<<512, 256, 0, stream>>>(att_bf, kvs_k, vT, tmp_bf, l);
    add_ln_kernel<<<kRows / 4, 256, 0, stream>>>(att, tmp_bf, ln1_g + l * kHA,
                                                 ln1_b + l * kHA, att_bf);
    gemm_ff_kernel<true><<<dim3(kM / 64, kRows / 128), 256, 0, stream>>>(
        att_bf, ffw_t + (size_t)(l * 3) * 262144, ff_b1 + l * kM, ff1_bf);
    gemm_ff_kernel<true><<<dim3(kM / 64, kRows / 128), 256, 0, stream>>>(
        ff1_bf, ffw_t + (size_t)(l * 3 + 1) * 262144, ff_b2 + l * kM, ff2_bf);
    gemm_ff_kernel<false><<<dim3(kHA / 64, kRows / 128), 256, 0, stream>>>(
        ff2_bf, ffw_t + (size_t)(l * 3 + 2) * 262144, ff_b3 + l * kHA, tmp_bf);
    if (l < kL - 1)
      add_ln_kernel<<<kRows / 4, 256, 0, stream>>>(att, tmp_bf,
                                                   ln2_g + l * kHA,
                                                   ln2_b + l * kHA, att_bf);
  }
  // final LN2 fused into de_loss (att holds LN1-out y of layer 3; tmp_bf = ff3)
  de_loss_kernel<<<64, 256, 0, stream>>>(att, tmp_bf, ln2_g + 3 * kHA,
                                         ln2_b + 3 * kHA, de_wt, de_b, pred_u,
                                         out);
}